// Round 4
// baseline (1049.536 us; speedup 1.0000x reference)
//
#include <hip/hip_runtime.h>

#define EPS_C 0.01f

typedef __attribute__((ext_vector_type(8))) short short8;
typedef __attribute__((ext_vector_type(4))) float f32x4;
typedef __attribute__((ext_vector_type(4))) unsigned short u16x4;
typedef __attribute__((ext_vector_type(8))) unsigned short u16x8;

// ---------- workspace layout (float offsets) ----------
#define WS_H    0        // 320*320
#define WS_C    102400   // 256*256 (P, factored in place, row-major: C[i][k]=L[i][k])
#define WS_CT   167936   // 256*256 (CT[i][k] = C[k][i] = L[k][i])
#define WS_Y    233472   // 256*256
#define WS_RHS  299008   // 256*64
#define WS_C1T  315392   // 256*64
#define WS_D11  331776   // 64*64
#define WS_WF   335872   // 256*328 fp32  [A | B1 | B2]
#define WS_WFH  419840   // 256*352 u16 = 45056 floats
#define WS_WFM  464896
#define WS_WFL  509952
#define WS_WG   555008   // 65536*64 fp32

__device__ __forceinline__ unsigned short f2bf(float f) {
    unsigned int u = __float_as_uint(f);
    unsigned int r = (u + 0x7fffu + ((u >> 16) & 1u)) >> 16;
    return (unsigned short)r;
}
__device__ __forceinline__ float bf2f(unsigned short h) {
    return __uint_as_float(((unsigned int)h) << 16);
}

// ---------------- setup: P and H builds ----------------
__global__ void k_build(const float* __restrict__ Xm, const float* __restrict__ XPm,
                        float* __restrict__ H, float* __restrict__ P) {
    int idx = blockIdx.x * 256 + threadIdx.x;
    if (idx < 102400) {
        int i = idx / 320, j = idx - i * 320;
        const float4* a = (const float4*)(Xm + i * 320);
        const float4* b = (const float4*)(Xm + j * 320);
        float s = 0.f;
        for (int k = 0; k < 80; ++k) {
            float4 va = a[k], vb = b[k];
            s += va.x * vb.x + va.y * vb.y + va.z * vb.z + va.w * vb.w;
        }
        H[idx] = (i == j) ? s + EPS_C : s;
    } else {
        idx -= 102400;
        if (idx < 65536) {
            int i = idx >> 8, j = idx & 255;
            const float4* a = (const float4*)(XPm + i * 256);
            const float4* b = (const float4*)(XPm + j * 256);
            float s = 0.f;
            for (int k = 0; k < 64; ++k) {
                float4 va = a[k], vb = b[k];
                s += va.x * vb.x + va.y * vb.y + va.z * vb.z + va.w * vb.w;
            }
            P[idx] = (i == j) ? s + EPS_C : s;
        }
    }
}

// ---------------- setup: derived small matrices ----------------
__global__ void k_derived(const float* __restrict__ H, const float* __restrict__ Um,
                          const float* __restrict__ Y1, const float* __restrict__ B2,
                          float* __restrict__ Y, float* __restrict__ RHS,
                          float* __restrict__ C1T, float* __restrict__ D11g,
                          float* __restrict__ Wf) {
    int idx = blockIdx.x * 256 + threadIdx.x;
    if (idx < 65536) {
        int i = idx >> 8, j = idx & 255;
        Y[idx] = -0.5f * (H[i * 320 + j] + Y1[i * 256 + j] - Y1[j * 256 + i]);
        return;
    }
    idx -= 65536;
    if (idx < 16384) { // RHS = -H12 - U
        RHS[idx] = -H[(idx >> 6) * 320 + 256 + (idx & 63)] - Um[idx];
        return;
    }
    idx -= 16384;
    if (idx < 16384) { // C1T[d][q] = U[d][q]/lam[q]
        int q = idx & 63;
        float lam = 0.5f * H[(256 + q) * 320 + 256 + q];
        C1T[idx] = Um[idx] / lam;
        return;
    }
    idx -= 16384;
    if (idx < 4096) { // D11[q][j]
        int q = idx >> 6, j = idx & 63;
        float lam = 0.5f * H[(256 + q) * 320 + 256 + q];
        D11g[idx] = (j < q) ? -H[(256 + q) * 320 + 256 + j] / lam : 0.f;
        return;
    }
    idx -= 4096;
    if (idx < 2048) { // Wf tail: B2 at cols 320..327
        int o = idx >> 3, k = idx & 7;
        Wf[(size_t)o * 328 + 320 + k] = B2[idx];
    }
}

// ---------------- setup: blocked Cholesky, 1 block, latency-optimized ----------------
// C row-major, in-place: C[i][k] = L[i][k] (i>=k). Upper triangle becomes garbage (never read).
__global__ void __launch_bounds__(256) k_chol2(float* __restrict__ C) {
    __shared__ __align__(16) float Lb[64 * 68];
    __shared__ __align__(16) float panT[64 * 200]; // [col][row] transposed panel
    __shared__ float dinv_s[64];
    const int tid = threadIdx.x;
    const int lane = tid & 63, wid = tid >> 6;
    const int ig = tid & 15, jg = tid >> 4;
    for (int s = 0; s < 4; ++s) {
        const int k0 = s * 64;
        const int k1 = k0 + 64;
        const int R = 256 - k1;
        // Phase A: wave-register Cholesky of 64x64 diag block (wave 0 only)
        if (wid == 0) {
            float a[64];
            const float4* rp = (const float4*)&C[(size_t)(k0 + lane) * 256 + k0];
#pragma unroll
            for (int t = 0; t < 16; ++t) {
                float4 v = rp[t];
                a[4 * t] = v.x; a[4 * t + 1] = v.y; a[4 * t + 2] = v.z; a[4 * t + 3] = v.w;
            }
#pragma unroll
            for (int k = 0; k < 64; ++k) {
                float akk = __shfl(a[k], k);
                float d = sqrtf(akk);
                float di = 1.0f / d;
                float l = a[k] * di;        // lane>k: L[lane][k]; lane==k: d
                if (lane == k) { a[k] = d; dinv_s[k] = di; }
                if (lane > k) a[k] = l;
#pragma unroll
                for (int j = k + 1; j < 64; ++j) {
                    float ljk = __shfl(a[k], j);   // L[j][k]
                    a[j] = fmaf(-l, ljk, a[j]);    // valid for lane>=j; junk in upper
                }
            }
#pragma unroll
            for (int j = 0; j < 64; ++j) Lb[lane * 68 + j] = a[j];
            float4* wp = (float4*)&C[(size_t)(k0 + lane) * 256 + k0];
#pragma unroll
            for (int t = 0; t < 16; ++t) {
                float4 v = {a[4 * t], a[4 * t + 1], a[4 * t + 2], a[4 * t + 3]};
                wp[t] = v;
            }
        }
        __syncthreads();
        if (R > 0) {
            // Phase B: TRSM rows below diag (one thread per row, row in registers)
            if (tid < R) {
                const int row = k1 + tid;
                float x[64];
                const float4* rp = (const float4*)&C[(size_t)row * 256 + k0];
#pragma unroll
                for (int t = 0; t < 16; ++t) {
                    float4 v = rp[t];
                    x[4 * t] = v.x; x[4 * t + 1] = v.y; x[4 * t + 2] = v.z; x[4 * t + 3] = v.w;
                }
#pragma unroll
                for (int k = 0; k < 64; ++k) {
                    float sacc = x[k];
                    const int kf = k >> 2;
#pragma unroll
                    for (int j4 = 0; j4 < kf; ++j4) {
                        float4 lv = *(const float4*)&Lb[k * 68 + j4 * 4];
                        sacc -= lv.x * x[4 * j4] + lv.y * x[4 * j4 + 1] + lv.z * x[4 * j4 + 2] + lv.w * x[4 * j4 + 3];
                    }
#pragma unroll
                    for (int j = kf * 4; j < k; ++j) sacc -= Lb[k * 68 + j] * x[j];
                    x[k] = sacc * dinv_s[k];
                }
                float4* wp = (float4*)&C[(size_t)row * 256 + k0];
#pragma unroll
                for (int t = 0; t < 16; ++t) {
                    float4 v = {x[4 * t], x[4 * t + 1], x[4 * t + 2], x[4 * t + 3]};
                    wp[t] = v;
                }
#pragma unroll
                for (int j = 0; j < 64; ++j) panT[j * 200 + tid] = x[j];
            }
            __syncthreads();
            // Phase C: SYRK trailing update (lower tiles only)
            const int nt = R >> 2;
            for (int jt = jg; jt < nt; jt += 16)
                for (int it = ig; it < nt; it += 16) {
                    if (it < jt) continue;
                    const int i0 = k1 + it * 4, j0 = k1 + jt * 4;
                    float4 a0 = *(float4*)&C[(size_t)(i0 + 0) * 256 + j0];
                    float4 a1 = *(float4*)&C[(size_t)(i0 + 1) * 256 + j0];
                    float4 a2 = *(float4*)&C[(size_t)(i0 + 2) * 256 + j0];
                    float4 a3 = *(float4*)&C[(size_t)(i0 + 3) * 256 + j0];
                    for (int c = 0; c < 64; ++c) {
                        const float4 pj = *(const float4*)&panT[c * 200 + jt * 4];
                        const float4 pi = *(const float4*)&panT[c * 200 + it * 4];
                        a0.x -= pi.x * pj.x; a0.y -= pi.x * pj.y; a0.z -= pi.x * pj.z; a0.w -= pi.x * pj.w;
                        a1.x -= pi.y * pj.x; a1.y -= pi.y * pj.y; a1.z -= pi.y * pj.z; a1.w -= pi.y * pj.w;
                        a2.x -= pi.z * pj.x; a2.y -= pi.z * pj.y; a2.z -= pi.z * pj.z; a2.w -= pi.z * pj.w;
                        a3.x -= pi.w * pj.x; a3.y -= pi.w * pj.y; a3.z -= pi.w * pj.z; a3.w -= pi.w * pj.w;
                    }
                    *(float4*)&C[(size_t)(i0 + 0) * 256 + j0] = a0;
                    *(float4*)&C[(size_t)(i0 + 1) * 256 + j0] = a1;
                    *(float4*)&C[(size_t)(i0 + 2) * 256 + j0] = a2;
                    *(float4*)&C[(size_t)(i0 + 3) * 256 + j0] = a3;
                }
        }
        __syncthreads();
    }
}

__global__ void k_transp(const float* __restrict__ C, float* __restrict__ CT) {
    int idx = blockIdx.x * 256 + threadIdx.x;
    int i = idx >> 8, k = idx & 255;
    CT[idx] = C[k * 256 + i];
}

// ---------------- setup: blocked triangular solves, 5 blocks x 64 columns ----------------
#define VTS 261
__global__ void __launch_bounds__(256) k_solve2(const float* __restrict__ C, const float* __restrict__ CT,
                                                const float* __restrict__ Y, const float* __restrict__ RHS,
                                                float* __restrict__ Wf) {
    __shared__ __align__(16) float Vt[64 * VTS];   // [col][row]
    __shared__ __align__(16) float Lb[64 * 68];
    __shared__ __align__(16) float LbT[64 * 68];
    __shared__ float dinv_s[64];
    const int tid = threadIdx.x;
    const int cc0 = blockIdx.x * 64;
    const int c = tid & 63, seg = tid >> 6;
    // load G columns
    for (int i = 0; i < 64; ++i) {
        int r = seg * 64 + i;
        float g = (cc0 < 256) ? Y[(size_t)r * 256 + cc0 + c] : RHS[(size_t)r * 64 + c];
        Vt[c * VTS + r] = g;
    }
    __syncthreads();
    // FORWARD: L V = G
    for (int b = 0; b < 4; ++b) {
        const int rb = b * 64;
        for (int e = tid; e < 4096; e += 256) {
            int i = e >> 6, j = e & 63;
            Lb[i * 68 + j] = C[(size_t)(rb + i) * 256 + rb + j];
        }
        if (tid < 64) dinv_s[tid] = 1.0f / C[(size_t)(rb + tid) * 256 + rb + tid];
        __syncthreads();
        if (tid < 64) { // diag solve, one thread per column
            float v[64];
#pragma unroll
            for (int k = 0; k < 64; ++k) v[k] = Vt[tid * VTS + rb + k];
#pragma unroll
            for (int k = 0; k < 64; ++k) {
                float sacc = v[k];
                const int kf = k >> 2;
#pragma unroll
                for (int j4 = 0; j4 < kf; ++j4) {
                    float4 lv = *(const float4*)&Lb[k * 68 + j4 * 4];
                    sacc -= lv.x * v[4 * j4] + lv.y * v[4 * j4 + 1] + lv.z * v[4 * j4 + 2] + lv.w * v[4 * j4 + 3];
                }
#pragma unroll
                for (int j = kf * 4; j < k; ++j) sacc -= Lb[k * 68 + j] * v[j];
                v[k] = sacc * dinv_s[k];
            }
#pragma unroll
            for (int k = 0; k < 64; ++k) Vt[tid * VTS + rb + k] = v[k];
        }
        __syncthreads();
        if (b < 3) { // update rows below
            float z[64];
#pragma unroll
            for (int k = 0; k < 64; ++k) z[k] = Vt[c * VTS + rb + k];
            const int k1b = rb + 64;
            const int rows_per_seg = (192 - rb) >> 2;
            for (int i = 0; i < rows_per_seg; ++i) {
                const int r = k1b + seg * rows_per_seg + i;
                float acc = Vt[c * VTS + r];
                const float4* lrow = (const float4*)&C[(size_t)r * 256 + rb];
#pragma unroll
                for (int k4 = 0; k4 < 16; ++k4) {
                    float4 lv = lrow[k4];
                    acc -= lv.x * z[4 * k4] + lv.y * z[4 * k4 + 1] + lv.z * z[4 * k4 + 2] + lv.w * z[4 * k4 + 3];
                }
                Vt[c * VTS + r] = acc;
            }
        }
        __syncthreads();
    }
    // BACKWARD: L^T Z = V
    for (int b = 3; b >= 0; --b) {
        const int rb = b * 64;
        for (int e = tid; e < 4096; e += 256) {
            int i = e >> 6, j = e & 63;
            LbT[i * 68 + j] = CT[(size_t)(rb + i) * 256 + rb + j]; // = L[rb+j][rb+i]
        }
        if (tid < 64) dinv_s[tid] = 1.0f / C[(size_t)(rb + tid) * 256 + rb + tid];
        __syncthreads();
        if (tid < 64) {
            float v[64];
#pragma unroll
            for (int k = 0; k < 64; ++k) v[k] = Vt[tid * VTS + rb + k];
#pragma unroll
            for (int kk = 0; kk < 64; ++kk) {
                const int k = 63 - kk;
                float sacc = v[k];
                const int jstart = k + 1;
                const int jal = (jstart + 3) & ~3;
#pragma unroll
                for (int j = jstart; j < jal && j < 64; ++j) sacc -= LbT[k * 68 + j] * v[j];
#pragma unroll
                for (int j4 = (jstart + 3) >> 2; j4 < 16; ++j4) {
                    float4 lv = *(const float4*)&LbT[k * 68 + j4 * 4];
                    sacc -= lv.x * v[4 * j4] + lv.y * v[4 * j4 + 1] + lv.z * v[4 * j4 + 2] + lv.w * v[4 * j4 + 3];
                }
                v[k] = sacc * dinv_s[k];
            }
#pragma unroll
            for (int k = 0; k < 64; ++k) Vt[tid * VTS + rb + k] = v[k];
        }
        __syncthreads();
        if (b > 0) { // update rows above
            float z[64];
#pragma unroll
            for (int k = 0; k < 64; ++k) z[k] = Vt[c * VTS + rb + k];
            const int rows_per_seg = rb >> 2;
            for (int i = 0; i < rows_per_seg; ++i) {
                const int r = seg * rows_per_seg + i;
                float acc = Vt[c * VTS + r];
                const float4* lrow = (const float4*)&CT[(size_t)r * 256 + rb];
#pragma unroll
                for (int k4 = 0; k4 < 16; ++k4) {
                    float4 lv = lrow[k4];
                    acc -= lv.x * z[4 * k4] + lv.y * z[4 * k4 + 1] + lv.z * z[4 * k4 + 2] + lv.w * z[4 * k4 + 3];
                }
                Vt[c * VTS + r] = acc;
            }
        }
        __syncthreads();
    }
    // write out: Wf[:, cc0..cc0+63]
    for (int i = 0; i < 64; ++i) {
        int r = seg * 64 + i;
        Wf[(size_t)r * 328 + cc0 + c] = Vt[c * VTS + r];
    }
}

// ---------------- pack Wf -> 3-way bf16 split, layout [A | B2 | 0 | B1], K=352 ----------------
__global__ void k_packWf3(const float* __restrict__ Wf, unsigned short* __restrict__ Bh,
                          unsigned short* __restrict__ Bm, unsigned short* __restrict__ Bl) {
    int idx = blockIdx.x * 256 + threadIdx.x; // 256*352 = 90112
    if (idx >= 90112) return;
    int n = idx / 352, k = idx - n * 352;
    float f;
    if (k < 256)      f = Wf[(size_t)n * 328 + k];               // A
    else if (k < 264) f = Wf[(size_t)n * 328 + 320 + (k - 256)]; // B2
    else if (k < 288) f = 0.f;                                    // pad
    else              f = Wf[(size_t)n * 328 + 256 + (k - 288)]; // B1
    unsigned short h = f2bf(f);
    float r1 = f - bf2f(h);
    unsigned short m = f2bf(r1);
    float r2 = r1 - bf2f(m);
    unsigned short l = f2bf(r2);
    Bh[idx] = h; Bm[idx] = m; Bl[idx] = l;
}

// ---------------- main 1: base + recurrence -> w (fp32) ----------------
__global__ void __launch_bounds__(256) k_m1(const float* __restrict__ x, const float* __restrict__ u,
                                            const float* __restrict__ C1T, const float* __restrict__ D12,
                                            const float* __restrict__ bv, const float* __restrict__ D11g,
                                            float* __restrict__ wg) {
    __shared__ __align__(16) float sbuf[32 * 257]; // x chunk, k-major
    __shared__ float us[256 * 9];
    const int tid = threadIdx.x;
    const int r0 = blockIdx.x * 256;
#pragma unroll
    for (int i = 0; i < 8; ++i) {
        int e = tid + i * 256, r = e >> 3, j = e & 7;
        us[r * 9 + j] = u[(size_t)(r0 + r) * 8 + j];
    }
    float w[64];
#pragma unroll
    for (int q = 0; q < 64; ++q) w[q] = bv[q];
    const float4* xg4 = (const float4*)x;
    for (int kc = 0; kc < 8; ++kc) {
        __syncthreads();
#pragma unroll
        for (int i = 0; i < 8; ++i) {
            int e = tid + i * 256, r = e >> 3, c4 = e & 7;
            float4 v = xg4[(size_t)(r0 + r) * 64 + kc * 8 + c4];
            sbuf[(c4 * 4 + 0) * 257 + r] = v.x;
            sbuf[(c4 * 4 + 1) * 257 + r] = v.y;
            sbuf[(c4 * 4 + 2) * 257 + r] = v.z;
            sbuf[(c4 * 4 + 3) * 257 + r] = v.w;
        }
        __syncthreads();
        const float* c1p = C1T + kc * 32 * 64;
#pragma unroll 4
        for (int k = 0; k < 32; ++k) {
            float xv = sbuf[k * 257 + tid];
#pragma unroll
            for (int q = 0; q < 64; ++q) w[q] = fmaf(xv, c1p[k * 64 + q], w[q]);
        }
    }
#pragma unroll
    for (int j = 0; j < 8; ++j) {
        float uv = us[tid * 9 + j];
#pragma unroll
        for (int q = 0; q < 64; ++q) w[q] = fmaf(uv, D12[q * 8 + j], w[q]);
    }
    w[0] = fmaxf(w[0], 0.f);
#pragma unroll
    for (int i = 1; i < 64; ++i) {
        float s = w[i];
#pragma unroll
        for (int j = 0; j < i; ++j) s = fmaf(w[j], D11g[i * 64 + j], s);
        w[i] = fmaxf(s, 0.f);
    }
    float* wr = wg + (size_t)(r0 + tid) * 64;
#pragma unroll
    for (int c = 0; c < 16; ++c) {
        float4 v = {w[4 * c], w[4 * c + 1], w[4 * c + 2], w[4 * c + 3]};
        *(float4*)&wr[c * 4] = v;
    }
}

// ---------------- main 2: out = [x|u|0|w] @ WfP^T via tiered bf16x3-split MFMA ----------------
#define ASTR 360
__global__ void __launch_bounds__(256) k_m2(const float* __restrict__ x, const float* __restrict__ wg,
                                            const float* __restrict__ u,
                                            const unsigned short* __restrict__ Bh,
                                            const unsigned short* __restrict__ Bm,
                                            const unsigned short* __restrict__ Bl,
                                            float* __restrict__ out) {
    __shared__ __align__(16) unsigned short Ah[32 * ASTR];
    __shared__ __align__(16) unsigned short Am[32 * ASTR];
    __shared__ __align__(16) unsigned short Al[32 * ASTR];
    const int tid = threadIdx.x;
    const int r0 = blockIdx.x * 32;
    {
        const float4* xg4 = (const float4*)(x + (size_t)r0 * 256);
#pragma unroll
        for (int i = 0; i < 8; ++i) {
            int e = tid + i * 256, r = e >> 6, c4 = e & 63;
            float4 v = xg4[e];
            float vv[4] = {v.x, v.y, v.z, v.w};
            u16x4 hv, mv, lv;
#pragma unroll
            for (int j = 0; j < 4; ++j) {
                unsigned short h = f2bf(vv[j]);
                float rr1 = vv[j] - bf2f(h);
                unsigned short m = f2bf(rr1);
                lv[j] = f2bf(rr1 - bf2f(m));
                hv[j] = h; mv[j] = m;
            }
            *(u16x4*)&Ah[r * ASTR + c4 * 4] = hv;
            *(u16x4*)&Am[r * ASTR + c4 * 4] = mv;
            *(u16x4*)&Al[r * ASTR + c4 * 4] = lv;
        }
    }
    if (tid < 64) {
        int r = tid >> 1, h4 = tid & 1;
        float4 v = *(const float4*)&u[(size_t)(r0 + r) * 8 + h4 * 4];
        float vv[4] = {v.x, v.y, v.z, v.w};
        u16x4 hv, mv, lv;
#pragma unroll
        for (int j = 0; j < 4; ++j) {
            unsigned short h = f2bf(vv[j]);
            float rr1 = vv[j] - bf2f(h);
            unsigned short m = f2bf(rr1);
            lv[j] = f2bf(rr1 - bf2f(m));
            hv[j] = h; mv[j] = m;
        }
        *(u16x4*)&Ah[r * ASTR + 256 + h4 * 4] = hv;
        *(u16x4*)&Am[r * ASTR + 256 + h4 * 4] = mv;
        *(u16x4*)&Al[r * ASTR + 256 + h4 * 4] = lv;
    }
    if (tid < 96) {
        int r = tid / 3, cc = tid - r * 3;
        u16x8 z = {0, 0, 0, 0, 0, 0, 0, 0};
        *(u16x8*)&Ah[r * ASTR + 264 + cc * 8] = z;
        *(u16x8*)&Am[r * ASTR + 264 + cc * 8] = z;
        *(u16x8*)&Al[r * ASTR + 264 + cc * 8] = z;
    }
    {
        int r = tid >> 3, c8 = tid & 7;
        const float4* wp = (const float4*)&wg[(size_t)(r0 + r) * 64 + c8 * 8];
        float4 v0 = wp[0], v1 = wp[1];
        float vv[8] = {v0.x, v0.y, v0.z, v0.w, v1.x, v1.y, v1.z, v1.w};
        u16x8 hv, mv, lv;
#pragma unroll
        for (int j = 0; j < 8; ++j) {
            unsigned short h = f2bf(vv[j]);
            float rr1 = vv[j] - bf2f(h);
            unsigned short m = f2bf(rr1);
            lv[j] = f2bf(rr1 - bf2f(m));
            hv[j] = h; mv[j] = m;
        }
        *(u16x8*)&Ah[r * ASTR + 288 + c8 * 8] = hv;
        *(u16x8*)&Am[r * ASTR + 288 + c8 * 8] = mv;
        *(u16x8*)&Al[r * ASTR + 288 + c8 * 8] = lv;
    }
    __syncthreads();

    const int lane = tid & 63, wid = tid >> 6;
    const int n0 = wid * 64;
    const int lr = lane & 15, lg = lane >> 4;
    const int lk = lg * 8;
    f32x4 acc[2][4];
#pragma unroll
    for (int m = 0; m < 2; ++m)
#pragma unroll
        for (int nf = 0; nf < 4; ++nf) acc[m][nf] = (f32x4){0.f, 0.f, 0.f, 0.f};

    for (int kt = 0; kt < 11; ++kt) {
        const int ka = kt * 32 + lk;
        short8 a_h[2], a_m[2], a_l[2];
        a_h[0] = *(const short8*)&Ah[lr * ASTR + ka];
        a_h[1] = *(const short8*)&Ah[(16 + lr) * ASTR + ka];
        a_m[0] = *(const short8*)&Am[lr * ASTR + ka];
        a_m[1] = *(const short8*)&Am[(16 + lr) * ASTR + ka];
        a_l[0] = *(const short8*)&Al[lr * ASTR + ka];
        a_l[1] = *(const short8*)&Al[(16 + lr) * ASTR + ka];
        short8 b_h[4], b_m[4], b_l[4];
#pragma unroll
        for (int nf = 0; nf < 4; ++nf) {
            const size_t n = (size_t)(n0 + nf * 16 + lr);
            b_h[nf] = *(const short8*)&Bh[n * 352 + ka];
            b_m[nf] = *(const short8*)&Bm[n * 352 + ka];
            b_l[nf] = *(const short8*)&Bl[n * 352 + ka];
        }
        const bool wtile = (kt >= 9);
#pragma unroll
        for (int m = 0; m < 2; ++m)
#pragma unroll
            for (int nf = 0; nf < 4; ++nf) {
                acc[m][nf] = __builtin_amdgcn_mfma_f32_16x16x32_bf16(a_h[m], b_h[nf], acc[m][nf], 0, 0, 0);
                acc[m][nf] = __builtin_amdgcn_mfma_f32_16x16x32_bf16(a_m[m], b_h[nf], acc[m][nf], 0, 0, 0);
                acc[m][nf] = __builtin_amdgcn_mfma_f32_16x16x32_bf16(a_h[m], b_m[nf], acc[m][nf], 0, 0, 0);
                acc[m][nf] = __builtin_amdgcn_mfma_f32_16x16x32_bf16(a_l[m], b_h[nf], acc[m][nf], 0, 0, 0);
                acc[m][nf] = __builtin_amdgcn_mfma_f32_16x16x32_bf16(a_m[m], b_m[nf], acc[m][nf], 0, 0, 0);
                acc[m][nf] = __builtin_amdgcn_mfma_f32_16x16x32_bf16(a_h[m], b_l[nf], acc[m][nf], 0, 0, 0);
                if (wtile) {
                    acc[m][nf] = __builtin_amdgcn_mfma_f32_16x16x32_bf16(a_m[m], b_l[nf], acc[m][nf], 0, 0, 0);
                    acc[m][nf] = __builtin_amdgcn_mfma_f32_16x16x32_bf16(a_l[m], b_m[nf], acc[m][nf], 0, 0, 0);
                }
            }
    }
#pragma unroll
    for (int m = 0; m < 2; ++m)
#pragma unroll
        for (int nf = 0; nf < 4; ++nf)
#pragma unroll
            for (int j = 0; j < 4; ++j)
                out[(size_t)(r0 + m * 16 + lg * 4 + j) * 256 + n0 + nf * 16 + lr] = acc[m][nf][j];
}

extern "C" void kernel_launch(void* const* d_in, const int* in_sizes, int n_in,
                              void* d_out, int out_size, void* d_ws, size_t ws_size,
                              hipStream_t stream) {
    const float* x   = (const float*)d_in[0];
    const float* u   = (const float*)d_in[1];
    const float* Xm  = (const float*)d_in[2];
    const float* Um  = (const float*)d_in[3];
    const float* Y1  = (const float*)d_in[4];
    const float* XPm = (const float*)d_in[5];
    const float* B2  = (const float*)d_in[6];
    const float* D12 = (const float*)d_in[7];
    const float* bv  = (const float*)d_in[8];
    float* out = (float*)d_out;
    float* ws  = (float*)d_ws;

    float* H    = ws + WS_H;
    float* C    = ws + WS_C;
    float* CT   = ws + WS_CT;
    float* Y    = ws + WS_Y;
    float* RHS  = ws + WS_RHS;
    float* C1T  = ws + WS_C1T;
    float* D11g = ws + WS_D11;
    float* Wf   = ws + WS_WF;
    unsigned short* Bh = (unsigned short*)(ws + WS_WFH);
    unsigned short* Bm = (unsigned short*)(ws + WS_WFM);
    unsigned short* Bl = (unsigned short*)(ws + WS_WFL);
    float* wg = ws + WS_WG;

    k_build<<<656, 256, 0, stream>>>(Xm, XPm, H, C);
    k_derived<<<408, 256, 0, stream>>>(H, Um, Y1, B2, Y, RHS, C1T, D11g, Wf);
    k_m1<<<256, 256, 0, stream>>>(x, u, C1T, D12, bv, D11g, wg);
    k_chol2<<<1, 256, 0, stream>>>(C);
    k_transp<<<256, 256, 0, stream>>>(C, CT);
    k_solve2<<<5, 256, 0, stream>>>(C, CT, Y, RHS, Wf);
    k_packWf3<<<352, 256, 0, stream>>>(Wf, Bh, Bm, Bl);
    k_m2<<<2048, 256, 0, stream>>>(x, wg, u, Bh, Bm, Bl, out);
}

// Round 5
// 991.523 us; speedup vs baseline: 1.0585x; 1.0585x over previous
//
#include <hip/hip_runtime.h>

#define EPS_C 0.01f

typedef __attribute__((ext_vector_type(8))) short short8;
typedef __attribute__((ext_vector_type(4))) float f32x4;
typedef __attribute__((ext_vector_type(4))) unsigned short u16x4;
typedef __attribute__((ext_vector_type(8))) unsigned short u16x8;

// ---------- workspace layout (float offsets) ----------
#define WS_H    0        // 320*320 (H; later reused as PI 256*256)
#define WS_C    102400   // 256*256 row-major L (in-place Cholesky of P)
#define WS_LI   167936   // 256*256 Linv (lower tri; upper zeroed)
#define WS_Y    233472   // 256*256
#define WS_RHS  299008   // 256*64
#define WS_C1T  315392   // 256*64
#define WS_D11  331776   // 64*64
#define WS_WF   335872   // 256*328 fp32  [A | B1 | B2]
#define WS_WFH  419840   // 256*352 u16 each
#define WS_WFM  464896
#define WS_WFL  509952
#define WS_WG   555008   // 65536*64 fp32

__device__ __forceinline__ unsigned short f2bf(float f) {
    unsigned int u = __float_as_uint(f);
    unsigned int r = (u + 0x7fffu + ((u >> 16) & 1u)) >> 16;
    return (unsigned short)r;
}
__device__ __forceinline__ float bf2f(unsigned short h) {
    return __uint_as_float(((unsigned int)h) << 16);
}

// ---------------- setup: P and H builds ----------------
__global__ void k_build(const float* __restrict__ Xm, const float* __restrict__ XPm,
                        float* __restrict__ H, float* __restrict__ P) {
    int idx = blockIdx.x * 256 + threadIdx.x;
    if (idx < 102400) {
        int i = idx / 320, j = idx - i * 320;
        const float4* a = (const float4*)(Xm + i * 320);
        const float4* b = (const float4*)(Xm + j * 320);
        float s = 0.f;
        for (int k = 0; k < 80; ++k) {
            float4 va = a[k], vb = b[k];
            s += va.x * vb.x + va.y * vb.y + va.z * vb.z + va.w * vb.w;
        }
        H[idx] = (i == j) ? s + EPS_C : s;
    } else {
        idx -= 102400;
        if (idx < 65536) {
            int i = idx >> 8, j = idx & 255;
            const float4* a = (const float4*)(XPm + i * 256);
            const float4* b = (const float4*)(XPm + j * 256);
            float s = 0.f;
            for (int k = 0; k < 64; ++k) {
                float4 va = a[k], vb = b[k];
                s += va.x * vb.x + va.y * vb.y + va.z * vb.z + va.w * vb.w;
            }
            P[idx] = (i == j) ? s + EPS_C : s;
        }
    }
}

// ---------------- setup: derived small matrices + LI zero ----------------
__global__ void k_derived(const float* __restrict__ H, const float* __restrict__ Um,
                          const float* __restrict__ Y1, const float* __restrict__ B2,
                          float* __restrict__ Y, float* __restrict__ RHS,
                          float* __restrict__ C1T, float* __restrict__ D11g,
                          float* __restrict__ Wf, float* __restrict__ LI) {
    int idx = blockIdx.x * 256 + threadIdx.x;
    if (idx < 65536) {
        int i = idx >> 8, j = idx & 255;
        Y[idx] = -0.5f * (H[i * 320 + j] + Y1[i * 256 + j] - Y1[j * 256 + i]);
        return;
    }
    idx -= 65536;
    if (idx < 16384) { // RHS = -H12 - U
        RHS[idx] = -H[(idx >> 6) * 320 + 256 + (idx & 63)] - Um[idx];
        return;
    }
    idx -= 16384;
    if (idx < 16384) { // C1T[d][q] = U[d][q]/lam[q]
        int q = idx & 63;
        float lam = 0.5f * H[(256 + q) * 320 + 256 + q];
        C1T[idx] = Um[idx] / lam;
        return;
    }
    idx -= 16384;
    if (idx < 4096) { // D11[q][j]
        int q = idx >> 6, j = idx & 63;
        float lam = 0.5f * H[(256 + q) * 320 + 256 + q];
        D11g[idx] = (j < q) ? -H[(256 + q) * 320 + 256 + j] / lam : 0.f;
        return;
    }
    idx -= 4096;
    if (idx < 2048) { // Wf tail: B2 at cols 320..327
        int o = idx >> 3, k = idx & 7;
        Wf[(size_t)o * 328 + 320 + k] = B2[idx];
        return;
    }
    idx -= 2048;
    if (idx < 65536) LI[idx] = 0.f; // zero Linv (upper blocks stay 0)
}

// ---------------- panel: diag Cholesky (wave regs) + diag Linv + TRSM ----------------
__global__ void __launch_bounds__(256) k_panel(float* __restrict__ C, float* __restrict__ LI, int s) {
    const int k0 = s * 64, k1 = k0 + 64;
    const int R = 256 - k1;
    __shared__ float Lb[64 * 65];
    __shared__ float dinv_s[64];
    __shared__ float xr[192 * 65];
    const int tid = threadIdx.x;
    const int lane = tid & 63, wid = tid >> 6;
    if (wid > 0) {
        // waves 1-3: stage below-panel rows (concurrent with wave 0's factorization)
        const int t = tid - 64;
        for (int e = t; e < R * 16; e += 192) {
            int r = e >> 4, c4 = e & 15;
            float4 v = *(const float4*)&C[(size_t)(k1 + r) * 256 + k0 + c4 * 4];
            xr[r * 65 + c4 * 4 + 0] = v.x;
            xr[r * 65 + c4 * 4 + 1] = v.y;
            xr[r * 65 + c4 * 4 + 2] = v.z;
            xr[r * 65 + c4 * 4 + 3] = v.w;
        }
    } else {
        // wave 0: register Cholesky of 64x64 diag block (lane = row)
        float a[64];
        const float4* rp = (const float4*)&C[(size_t)(k0 + lane) * 256 + k0];
#pragma unroll
        for (int t4 = 0; t4 < 16; ++t4) {
            float4 v = rp[t4];
            a[4 * t4] = v.x; a[4 * t4 + 1] = v.y; a[4 * t4 + 2] = v.z; a[4 * t4 + 3] = v.w;
        }
#pragma unroll
        for (int k = 0; k < 64; ++k) {
            float akk = __shfl(a[k], k);
            float d = sqrtf(akk);
            float di = 1.0f / d;
            float l = a[k] * di;
            if (lane == k) { a[k] = d; dinv_s[k] = di; }
            if (lane > k) a[k] = l;
#pragma unroll
            for (int j = k + 1; j < 64; ++j) {
                float ljk = __shfl(a[k], j);
                a[j] = fmaf(-l, ljk, a[j]);
            }
        }
#pragma unroll
        for (int j = 0; j < 64; ++j) Lb[lane * 65 + j] = a[j];
        {
            float4* wp = (float4*)&C[(size_t)(k0 + lane) * 256 + k0];
#pragma unroll
            for (int t4 = 0; t4 < 16; ++t4) {
                float4 v = {a[4 * t4], a[4 * t4 + 1], a[4 * t4 + 2], a[4 * t4 + 3]};
                wp[t4] = v;
            }
        }
        // diag-block Linv: lane = column; x[k<lane]=0 by induction
        {
            float x[64];
#pragma unroll
            for (int k = 0; k < 64; ++k) {
                float acc = (k == lane) ? 1.f : 0.f;
#pragma unroll
                for (int j = 0; j < k; ++j) acc = fmaf(-Lb[k * 65 + j], x[j], acc);
                x[k] = acc * dinv_s[k];
            }
#pragma unroll
            for (int k = 0; k < 64; ++k)
                LI[(size_t)(k0 + k) * 256 + k0 + lane] = (k >= lane) ? x[k] : 0.f;
        }
    }
    __syncthreads();
    // TRSM: row t of below-panel, dynamic loops, LDS row + broadcast Lb
    if (tid < R) {
        const int t = tid;
        for (int k = 0; k < 64; ++k) {
            float acc = xr[t * 65 + k];
            for (int j = 0; j < k; ++j) acc = fmaf(-Lb[k * 65 + j], xr[t * 65 + j], acc);
            xr[t * 65 + k] = acc * dinv_s[k];
        }
        float4* wp = (float4*)&C[(size_t)(k1 + t) * 256 + k0];
        for (int c4 = 0; c4 < 16; ++c4) {
            float4 v = {xr[t * 65 + c4 * 4], xr[t * 65 + c4 * 4 + 1],
                        xr[t * 65 + c4 * 4 + 2], xr[t * 65 + c4 * 4 + 3]};
            wp[c4] = v;
        }
    }
}

// ---------------- trailing SYRK update (multi-block) ----------------
__global__ void __launch_bounds__(256) k_trail(float* __restrict__ C, int s) {
    const int k0 = s * 64, k1 = k0 + 64;
    int bid = blockIdx.x;
    int bi = 0;
    while ((bi + 1) * (bi + 2) / 2 <= bid) ++bi;
    int bj = bid - bi * (bi + 1) / 2;
    const int i0 = k1 + bi * 64, j0 = k1 + bj * 64;
    __shared__ float Ps[64 * 65], Qs[64 * 65];
    const int tid = threadIdx.x;
    for (int e = tid; e < 1024; e += 256) {
        int r = e >> 4, c4 = e & 15;
        float4 v = *(const float4*)&C[(size_t)(i0 + r) * 256 + k0 + c4 * 4];
        Ps[r * 65 + c4 * 4 + 0] = v.x; Ps[r * 65 + c4 * 4 + 1] = v.y;
        Ps[r * 65 + c4 * 4 + 2] = v.z; Ps[r * 65 + c4 * 4 + 3] = v.w;
        if (bi != bj) {
            float4 w = *(const float4*)&C[(size_t)(j0 + r) * 256 + k0 + c4 * 4];
            Qs[r * 65 + c4 * 4 + 0] = w.x; Qs[r * 65 + c4 * 4 + 1] = w.y;
            Qs[r * 65 + c4 * 4 + 2] = w.z; Qs[r * 65 + c4 * 4 + 3] = w.w;
        }
    }
    __syncthreads();
    const float* Q = (bi == bj) ? Ps : Qs;
    const int ti = tid & 15, tj = tid >> 4;
    const int ib = i0 + ti * 4, jb = j0 + tj * 4;
    float acc[4][4];
#pragma unroll
    for (int r = 0; r < 4; ++r) {
        float4 cv = *(const float4*)&C[(size_t)(ib + r) * 256 + jb];
        acc[r][0] = cv.x; acc[r][1] = cv.y; acc[r][2] = cv.z; acc[r][3] = cv.w;
    }
    for (int c = 0; c < 64; ++c) {
        float pr[4], qc[4];
#pragma unroll
        for (int d = 0; d < 4; ++d) { pr[d] = Ps[(ti * 4 + d) * 65 + c]; qc[d] = Q[(tj * 4 + d) * 65 + c]; }
#pragma unroll
        for (int r = 0; r < 4; ++r)
#pragma unroll
            for (int d = 0; d < 4; ++d) acc[r][d] = fmaf(-pr[r], qc[d], acc[r][d]);
    }
#pragma unroll
    for (int r = 0; r < 4; ++r) {
        float4 v = {acc[r][0], acc[r][1], acc[r][2], acc[r][3]};
        *(float4*)&C[(size_t)(ib + r) * 256 + jb] = v;
    }
}

// ---------------- off-diagonal Linv blocks: X_ij = -Xii * (sum_k L_ik X_kj) ----------------
__global__ void __launch_bounds__(256) k_offdiag(const float* __restrict__ C, float* __restrict__ LI) {
    __shared__ float Ls[64 * 65], Xs[64 * 65], Ts[64 * 65];
    const int tid = threadIdx.x;
    const int ti = tid & 15, tj = tid >> 4;
#pragma unroll
    for (int p = 0; p < 6; ++p) {
        const int bi = (p == 0) ? 1 : (p == 1) ? 2 : (p == 2) ? 3 : (p == 3) ? 2 : (p == 4) ? 3 : 3;
        const int bj = (p == 0) ? 0 : (p == 1) ? 1 : (p == 2) ? 2 : (p == 3) ? 0 : (p == 4) ? 1 : 0;
        float t[4][4];
#pragma unroll
        for (int r = 0; r < 4; ++r)
#pragma unroll
            for (int d = 0; d < 4; ++d) t[r][d] = 0.f;
        for (int kb = bj; kb < bi; ++kb) {
            __syncthreads();
            for (int e = tid; e < 1024; e += 256) {
                int r = e >> 4, c4 = e & 15;
                float4 v = *(const float4*)&C[(size_t)(bi * 64 + r) * 256 + kb * 64 + c4 * 4];
                Ls[r * 65 + c4 * 4 + 0] = v.x; Ls[r * 65 + c4 * 4 + 1] = v.y;
                Ls[r * 65 + c4 * 4 + 2] = v.z; Ls[r * 65 + c4 * 4 + 3] = v.w;
                float4 w = *(const float4*)&LI[(size_t)(kb * 64 + r) * 256 + bj * 64 + c4 * 4];
                Xs[r * 65 + c4 * 4 + 0] = w.x; Xs[r * 65 + c4 * 4 + 1] = w.y;
                Xs[r * 65 + c4 * 4 + 2] = w.z; Xs[r * 65 + c4 * 4 + 3] = w.w;
            }
            __syncthreads();
            for (int c = 0; c < 64; ++c) {
                float lr[4], xc[4];
#pragma unroll
                for (int d = 0; d < 4; ++d) { lr[d] = Ls[(ti * 4 + d) * 65 + c]; xc[d] = Xs[c * 65 + tj * 4 + d]; }
#pragma unroll
                for (int r = 0; r < 4; ++r)
#pragma unroll
                    for (int d = 0; d < 4; ++d) t[r][d] = fmaf(lr[r], xc[d], t[r][d]);
            }
        }
        __syncthreads();
#pragma unroll
        for (int r = 0; r < 4; ++r)
#pragma unroll
            for (int d = 0; d < 4; ++d) Ts[(ti * 4 + r) * 65 + tj * 4 + d] = t[r][d];
        for (int e = tid; e < 1024; e += 256) {
            int r = e >> 4, c4 = e & 15;
            float4 v = *(const float4*)&LI[(size_t)(bi * 64 + r) * 256 + bi * 64 + c4 * 4];
            Ls[r * 65 + c4 * 4 + 0] = v.x; Ls[r * 65 + c4 * 4 + 1] = v.y;
            Ls[r * 65 + c4 * 4 + 2] = v.z; Ls[r * 65 + c4 * 4 + 3] = v.w;
        }
        __syncthreads();
        float o[4][4];
#pragma unroll
        for (int r = 0; r < 4; ++r)
#pragma unroll
            for (int d = 0; d < 4; ++d) o[r][d] = 0.f;
        for (int c = 0; c < 64; ++c) {
            float lr[4], tc[4];
#pragma unroll
            for (int d = 0; d < 4; ++d) { lr[d] = Ls[(ti * 4 + d) * 65 + c]; tc[d] = Ts[c * 65 + tj * 4 + d]; }
#pragma unroll
            for (int r = 0; r < 4; ++r)
#pragma unroll
                for (int d = 0; d < 4; ++d) o[r][d] = fmaf(lr[r], tc[d], o[r][d]);
        }
#pragma unroll
        for (int r = 0; r < 4; ++r) {
            float4 v = {-o[r][0], -o[r][1], -o[r][2], -o[r][3]};
            *(float4*)&LI[(size_t)(bi * 64 + ti * 4 + r) * 256 + bj * 64 + tj * 4] = v;
        }
        __syncthreads();
    }
}

// ---------------- PI = LI^T * LI ----------------
__global__ void __launch_bounds__(256) k_pinv(const float* __restrict__ LI, float* __restrict__ PI) {
    const int i0 = (blockIdx.x >> 2) * 64, j0 = (blockIdx.x & 3) * 64;
    __shared__ __align__(16) float As[64 * 68], Bs[64 * 68];
    const int tid = threadIdx.x;
    const int ti = tid & 15, tj = tid >> 4;
    float acc[4][4];
#pragma unroll
    for (int r = 0; r < 4; ++r)
#pragma unroll
        for (int d = 0; d < 4; ++d) acc[r][d] = 0.f;
    for (int kc = 0; kc < 4; ++kc) {
        __syncthreads();
        for (int e = tid; e < 1024; e += 256) {
            int kk = e >> 4, c4 = e & 15;
            float4 v = *(const float4*)&LI[(size_t)(kc * 64 + kk) * 256 + i0 + c4 * 4];
            *(float4*)&As[kk * 68 + c4 * 4] = v;
            float4 w = *(const float4*)&LI[(size_t)(kc * 64 + kk) * 256 + j0 + c4 * 4];
            *(float4*)&Bs[kk * 68 + c4 * 4] = w;
        }
        __syncthreads();
        for (int kk = 0; kk < 64; ++kk) {
            float4 av = *(const float4*)&As[kk * 68 + ti * 4];
            float4 bv = *(const float4*)&Bs[kk * 68 + tj * 4];
            float a4[4] = {av.x, av.y, av.z, av.w};
            float b4[4] = {bv.x, bv.y, bv.z, bv.w};
#pragma unroll
            for (int r = 0; r < 4; ++r)
#pragma unroll
                for (int d = 0; d < 4; ++d) acc[r][d] = fmaf(a4[r], b4[d], acc[r][d]);
        }
    }
#pragma unroll
    for (int r = 0; r < 4; ++r) {
        float4 v = {acc[r][0], acc[r][1], acc[r][2], acc[r][3]};
        *(float4*)&PI[(size_t)(i0 + ti * 4 + r) * 256 + j0 + tj * 4] = v;
    }
}

// ---------------- Wf[:,0:320] = PI @ [Y | RHS] ----------------
__global__ void __launch_bounds__(256) k_apply(const float* __restrict__ PI, const float* __restrict__ Y,
                                               const float* __restrict__ RHS, float* __restrict__ Wf) {
    const int i0 = (blockIdx.x / 5) * 64;
    const int c0 = (blockIdx.x % 5) * 64;
    __shared__ __align__(16) float Ps[64 * 68], Gs[64 * 68];
    const int tid = threadIdx.x;
    const int ti = tid & 15, tj = tid >> 4;
    float acc[4][4];
#pragma unroll
    for (int r = 0; r < 4; ++r)
#pragma unroll
        for (int d = 0; d < 4; ++d) acc[r][d] = 0.f;
    for (int kc = 0; kc < 4; ++kc) {
        __syncthreads();
        for (int e = tid; e < 1024; e += 256) {
            int i = e >> 4, k4 = e & 15;
            float4 v = *(const float4*)&PI[(size_t)(i0 + i) * 256 + kc * 64 + k4 * 4];
            Ps[(k4 * 4 + 0) * 68 + i] = v.x;
            Ps[(k4 * 4 + 1) * 68 + i] = v.y;
            Ps[(k4 * 4 + 2) * 68 + i] = v.z;
            Ps[(k4 * 4 + 3) * 68 + i] = v.w;
            int kk = e >> 4, c4 = e & 15;
            float4 w;
            if (c0 < 256) w = *(const float4*)&Y[(size_t)(kc * 64 + kk) * 256 + c0 + c4 * 4];
            else          w = *(const float4*)&RHS[(size_t)(kc * 64 + kk) * 64 + c4 * 4];
            *(float4*)&Gs[kk * 68 + c4 * 4] = w;
        }
        __syncthreads();
        for (int kk = 0; kk < 64; ++kk) {
            float4 pv = *(const float4*)&Ps[kk * 68 + ti * 4];
            float4 gv = *(const float4*)&Gs[kk * 68 + tj * 4];
            float p4[4] = {pv.x, pv.y, pv.z, pv.w};
            float g4[4] = {gv.x, gv.y, gv.z, gv.w};
#pragma unroll
            for (int r = 0; r < 4; ++r)
#pragma unroll
                for (int d = 0; d < 4; ++d) acc[r][d] = fmaf(p4[r], g4[d], acc[r][d]);
        }
    }
#pragma unroll
    for (int r = 0; r < 4; ++r) {
        float4 v = {acc[r][0], acc[r][1], acc[r][2], acc[r][3]};
        *(float4*)&Wf[(size_t)(i0 + ti * 4 + r) * 328 + c0 + tj * 4] = v;
    }
}

// ---------------- pack Wf -> 3-way bf16 split, layout [A | B2 | 0 | B1], K=352 ----------------
__global__ void k_packWf3(const float* __restrict__ Wf, unsigned short* __restrict__ Bh,
                          unsigned short* __restrict__ Bm, unsigned short* __restrict__ Bl) {
    int idx = blockIdx.x * 256 + threadIdx.x; // 256*352 = 90112
    if (idx >= 90112) return;
    int n = idx / 352, k = idx - n * 352;
    float f;
    if (k < 256)      f = Wf[(size_t)n * 328 + k];               // A
    else if (k < 264) f = Wf[(size_t)n * 328 + 320 + (k - 256)]; // B2
    else if (k < 288) f = 0.f;                                    // pad
    else              f = Wf[(size_t)n * 328 + 256 + (k - 288)]; // B1
    unsigned short h = f2bf(f);
    float r1 = f - bf2f(h);
    unsigned short m = f2bf(r1);
    float r2 = r1 - bf2f(m);
    unsigned short l = f2bf(r2);
    Bh[idx] = h; Bm[idx] = m; Bl[idx] = l;
}

// ---------------- main 1: base + recurrence -> w (fp32) ----------------
__global__ void __launch_bounds__(256) k_m1(const float* __restrict__ x, const float* __restrict__ u,
                                            const float* __restrict__ C1T, const float* __restrict__ D12,
                                            const float* __restrict__ bv, const float* __restrict__ D11g,
                                            float* __restrict__ wg) {
    __shared__ __align__(16) float sbuf[32 * 257];
    __shared__ float us[256 * 9];
    const int tid = threadIdx.x;
    const int r0 = blockIdx.x * 256;
#pragma unroll
    for (int i = 0; i < 8; ++i) {
        int e = tid + i * 256, r = e >> 3, j = e & 7;
        us[r * 9 + j] = u[(size_t)(r0 + r) * 8 + j];
    }
    float w[64];
#pragma unroll
    for (int q = 0; q < 64; ++q) w[q] = bv[q];
    const float4* xg4 = (const float4*)x;
    for (int kc = 0; kc < 8; ++kc) {
        __syncthreads();
#pragma unroll
        for (int i = 0; i < 8; ++i) {
            int e = tid + i * 256, r = e >> 3, c4 = e & 7;
            float4 v = xg4[(size_t)(r0 + r) * 64 + kc * 8 + c4];
            sbuf[(c4 * 4 + 0) * 257 + r] = v.x;
            sbuf[(c4 * 4 + 1) * 257 + r] = v.y;
            sbuf[(c4 * 4 + 2) * 257 + r] = v.z;
            sbuf[(c4 * 4 + 3) * 257 + r] = v.w;
        }
        __syncthreads();
        const float* c1p = C1T + kc * 32 * 64;
#pragma unroll 4
        for (int k = 0; k < 32; ++k) {
            float xv = sbuf[k * 257 + tid];
#pragma unroll
            for (int q = 0; q < 64; ++q) w[q] = fmaf(xv, c1p[k * 64 + q], w[q]);
        }
    }
#pragma unroll
    for (int j = 0; j < 8; ++j) {
        float uv = us[tid * 9 + j];
#pragma unroll
        for (int q = 0; q < 64; ++q) w[q] = fmaf(uv, D12[q * 8 + j], w[q]);
    }
    w[0] = fmaxf(w[0], 0.f);
#pragma unroll
    for (int i = 1; i < 64; ++i) {
        float s = w[i];
#pragma unroll
        for (int j = 0; j < i; ++j) s = fmaf(w[j], D11g[i * 64 + j], s);
        w[i] = fmaxf(s, 0.f);
    }
    float* wr = wg + (size_t)(r0 + tid) * 64;
#pragma unroll
    for (int c = 0; c < 16; ++c) {
        float4 v = {w[4 * c], w[4 * c + 1], w[4 * c + 2], w[4 * c + 3]};
        *(float4*)&wr[c * 4] = v;
    }
}

// ---------------- main 2: out = [x|u|0|w] @ WfP^T via tiered bf16x3-split MFMA ----------------
#define ASTR 360
__global__ void __launch_bounds__(256) k_m2(const float* __restrict__ x, const float* __restrict__ wg,
                                            const float* __restrict__ u,
                                            const unsigned short* __restrict__ Bh,
                                            const unsigned short* __restrict__ Bm,
                                            const unsigned short* __restrict__ Bl,
                                            float* __restrict__ out) {
    __shared__ __align__(16) unsigned short Ah[32 * ASTR];
    __shared__ __align__(16) unsigned short Am[32 * ASTR];
    __shared__ __align__(16) unsigned short Al[32 * ASTR];
    const int tid = threadIdx.x;
    const int r0 = blockIdx.x * 32;
    {
        const float4* xg4 = (const float4*)(x + (size_t)r0 * 256);
#pragma unroll
        for (int i = 0; i < 8; ++i) {
            int e = tid + i * 256, r = e >> 6, c4 = e & 63;
            float4 v = xg4[e];
            float vv[4] = {v.x, v.y, v.z, v.w};
            u16x4 hv, mv, lv;
#pragma unroll
            for (int j = 0; j < 4; ++j) {
                unsigned short h = f2bf(vv[j]);
                float rr1 = vv[j] - bf2f(h);
                unsigned short m = f2bf(rr1);
                lv[j] = f2bf(rr1 - bf2f(m));
                hv[j] = h; mv[j] = m;
            }
            *(u16x4*)&Ah[r * ASTR + c4 * 4] = hv;
            *(u16x4*)&Am[r * ASTR + c4 * 4] = mv;
            *(u16x4*)&Al[r * ASTR + c4 * 4] = lv;
        }
    }
    if (tid < 64) {
        int r = tid >> 1, h4 = tid & 1;
        float4 v = *(const float4*)&u[(size_t)(r0 + r) * 8 + h4 * 4];
        float vv[4] = {v.x, v.y, v.z, v.w};
        u16x4 hv, mv, lv;
#pragma unroll
        for (int j = 0; j < 4; ++j) {
            unsigned short h = f2bf(vv[j]);
            float rr1 = vv[j] - bf2f(h);
            unsigned short m = f2bf(rr1);
            lv[j] = f2bf(rr1 - bf2f(m));
            hv[j] = h; mv[j] = m;
        }
        *(u16x4*)&Ah[r * ASTR + 256 + h4 * 4] = hv;
        *(u16x4*)&Am[r * ASTR + 256 + h4 * 4] = mv;
        *(u16x4*)&Al[r * ASTR + 256 + h4 * 4] = lv;
    }
    if (tid < 96) {
        int r = tid / 3, cc = tid - r * 3;
        u16x8 z = {0, 0, 0, 0, 0, 0, 0, 0};
        *(u16x8*)&Ah[r * ASTR + 264 + cc * 8] = z;
        *(u16x8*)&Am[r * ASTR + 264 + cc * 8] = z;
        *(u16x8*)&Al[r * ASTR + 264 + cc * 8] = z;
    }
    {
        int r = tid >> 3, c8 = tid & 7;
        const float4* wp = (const float4*)&wg[(size_t)(r0 + r) * 64 + c8 * 8];
        float4 v0 = wp[0], v1 = wp[1];
        float vv[8] = {v0.x, v0.y, v0.z, v0.w, v1.x, v1.y, v1.z, v1.w};
        u16x8 hv, mv, lv;
#pragma unroll
        for (int j = 0; j < 8; ++j) {
            unsigned short h = f2bf(vv[j]);
            float rr1 = vv[j] - bf2f(h);
            unsigned short m = f2bf(rr1);
            lv[j] = f2bf(rr1 - bf2f(m));
            hv[j] = h; mv[j] = m;
        }
        *(u16x8*)&Ah[r * ASTR + 288 + c8 * 8] = hv;
        *(u16x8*)&Am[r * ASTR + 288 + c8 * 8] = mv;
        *(u16x8*)&Al[r * ASTR + 288 + c8 * 8] = lv;
    }
    __syncthreads();

    const int lane = tid & 63, wid = tid >> 6;
    const int n0 = wid * 64;
    const int lr = lane & 15, lg = lane >> 4;
    const int lk = lg * 8;
    f32x4 acc[2][4];
#pragma unroll
    for (int m = 0; m < 2; ++m)
#pragma unroll
        for (int nf = 0; nf < 4; ++nf) acc[m][nf] = (f32x4){0.f, 0.f, 0.f, 0.f};

    for (int kt = 0; kt < 11; ++kt) {
        const int ka = kt * 32 + lk;
        short8 a_h[2], a_m[2], a_l[2];
        a_h[0] = *(const short8*)&Ah[lr * ASTR + ka];
        a_h[1] = *(const short8*)&Ah[(16 + lr) * ASTR + ka];
        a_m[0] = *(const short8*)&Am[lr * ASTR + ka];
        a_m[1] = *(const short8*)&Am[(16 + lr) * ASTR + ka];
        a_l[0] = *(const short8*)&Al[lr * ASTR + ka];
        a_l[1] = *(const short8*)&Al[(16 + lr) * ASTR + ka];
        short8 b_h[4], b_m[4], b_l[4];
#pragma unroll
        for (int nf = 0; nf < 4; ++nf) {
            const size_t n = (size_t)(n0 + nf * 16 + lr);
            b_h[nf] = *(const short8*)&Bh[n * 352 + ka];
            b_m[nf] = *(const short8*)&Bm[n * 352 + ka];
            b_l[nf] = *(const short8*)&Bl[n * 352 + ka];
        }
        const bool wtile = (kt >= 9);
#pragma unroll
        for (int m = 0; m < 2; ++m)
#pragma unroll
            for (int nf = 0; nf < 4; ++nf) {
                acc[m][nf] = __builtin_amdgcn_mfma_f32_16x16x32_bf16(a_h[m], b_h[nf], acc[m][nf], 0, 0, 0);
                acc[m][nf] = __builtin_amdgcn_mfma_f32_16x16x32_bf16(a_m[m], b_h[nf], acc[m][nf], 0, 0, 0);
                acc[m][nf] = __builtin_amdgcn_mfma_f32_16x16x32_bf16(a_h[m], b_m[nf], acc[m][nf], 0, 0, 0);
                acc[m][nf] = __builtin_amdgcn_mfma_f32_16x16x32_bf16(a_l[m], b_h[nf], acc[m][nf], 0, 0, 0);
                acc[m][nf] = __builtin_amdgcn_mfma_f32_16x16x32_bf16(a_m[m], b_m[nf], acc[m][nf], 0, 0, 0);
                acc[m][nf] = __builtin_amdgcn_mfma_f32_16x16x32_bf16(a_h[m], b_l[nf], acc[m][nf], 0, 0, 0);
                if (wtile) {
                    acc[m][nf] = __builtin_amdgcn_mfma_f32_16x16x32_bf16(a_m[m], b_l[nf], acc[m][nf], 0, 0, 0);
                    acc[m][nf] = __builtin_amdgcn_mfma_f32_16x16x32_bf16(a_l[m], b_m[nf], acc[m][nf], 0, 0, 0);
                }
            }
    }
#pragma unroll
    for (int m = 0; m < 2; ++m)
#pragma unroll
        for (int nf = 0; nf < 4; ++nf)
#pragma unroll
            for (int j = 0; j < 4; ++j)
                out[(size_t)(r0 + m * 16 + lg * 4 + j) * 256 + n0 + nf * 16 + lr] = acc[m][nf][j];
}

extern "C" void kernel_launch(void* const* d_in, const int* in_sizes, int n_in,
                              void* d_out, int out_size, void* d_ws, size_t ws_size,
                              hipStream_t stream) {
    const float* x   = (const float*)d_in[0];
    const float* u   = (const float*)d_in[1];
    const float* Xm  = (const float*)d_in[2];
    const float* Um  = (const float*)d_in[3];
    const float* Y1  = (const float*)d_in[4];
    const float* XPm = (const float*)d_in[5];
    const float* B2  = (const float*)d_in[6];
    const float* D12 = (const float*)d_in[7];
    const float* bv  = (const float*)d_in[8];
    float* out = (float*)d_out;
    float* ws  = (float*)d_ws;

    float* H    = ws + WS_H;
    float* PI   = ws + WS_H;     // reuses H (dead after k_derived)
    float* C    = ws + WS_C;
    float* LI   = ws + WS_LI;
    float* Y    = ws + WS_Y;
    float* RHS  = ws + WS_RHS;
    float* C1T  = ws + WS_C1T;
    float* D11g = ws + WS_D11;
    float* Wf   = ws + WS_WF;
    unsigned short* Bh = (unsigned short*)(ws + WS_WFH);
    unsigned short* Bm = (unsigned short*)(ws + WS_WFM);
    unsigned short* Bl = (unsigned short*)(ws + WS_WFL);
    float* wg = ws + WS_WG;

    k_build<<<656, 256, 0, stream>>>(Xm, XPm, H, C);
    k_derived<<<664, 256, 0, stream>>>(H, Um, Y1, B2, Y, RHS, C1T, D11g, Wf, LI);
    k_m1<<<256, 256, 0, stream>>>(x, u, C1T, D12, bv, D11g, wg);
    k_panel<<<1, 256, 0, stream>>>(C, LI, 0);
    k_trail<<<6, 256, 0, stream>>>(C, 0);
    k_panel<<<1, 256, 0, stream>>>(C, LI, 1);
    k_trail<<<3, 256, 0, stream>>>(C, 1);
    k_panel<<<1, 256, 0, stream>>>(C, LI, 2);
    k_trail<<<1, 256, 0, stream>>>(C, 2);
    k_panel<<<1, 256, 0, stream>>>(C, LI, 3);
    k_offdiag<<<1, 256, 0, stream>>>(C, LI);
    k_pinv<<<16, 256, 0, stream>>>(LI, PI);
    k_apply<<<20, 256, 0, stream>>>(PI, Y, RHS, Wf);
    k_packWf3<<<352, 256, 0, stream>>>(Wf, Bh, Bm, Bl);
    k_m2<<<2048, 256, 0, stream>>>(x, wg, u, Bh, Bm, Bl, out);
}

// Round 6
// 610.163 us; speedup vs baseline: 1.7201x; 1.6250x over previous
//
#include <hip/hip_runtime.h>

#define EPS_C 0.01f

typedef __attribute__((ext_vector_type(8))) short short8;
typedef __attribute__((ext_vector_type(4))) float f32x4;
typedef __attribute__((ext_vector_type(4))) unsigned short u16x4;
typedef __attribute__((ext_vector_type(8))) unsigned short u16x8;

// ---------- workspace layout (float offsets) ----------
#define WS_H    0        // 320*320
#define WS_C    102400   // 256*256  P -> (block GJ) -> Pinv, in place
#define WS_T    167936   // 256*64   T = A[:,b] * E
#define WS_R    184320   // 64*256   R = old A[b,:]
#define WS_W    200704   // 64*256   W = E * A[b,:]
#define WS_E    217088   // 64*64    E = inv(A_bb)
#define WS_Y    233472   // 256*256
#define WS_RHS  299008   // 256*64
#define WS_C1T  315392   // 256*64
#define WS_D11  331776   // 64*64
#define WS_WF   335872   // 256*328 fp32  [A | B1 | B2]
#define WS_WFH  419840   // 256*352 u16 each
#define WS_WFM  464896
#define WS_WFL  509952
#define WS_WG   555008   // 65536*64 fp32

__device__ __forceinline__ unsigned short f2bf(float f) {
    unsigned int u = __float_as_uint(f);
    unsigned int r = (u + 0x7fffu + ((u >> 16) & 1u)) >> 16;
    return (unsigned short)r;
}
__device__ __forceinline__ float bf2f(unsigned short h) {
    return __uint_as_float(((unsigned int)h) << 16);
}

// ---------------- setup: P and H builds ----------------
__global__ void k_build(const float* __restrict__ Xm, const float* __restrict__ XPm,
                        float* __restrict__ H, float* __restrict__ P) {
    int idx = blockIdx.x * 256 + threadIdx.x;
    if (idx < 102400) {
        int i = idx / 320, j = idx - i * 320;
        const float4* a = (const float4*)(Xm + i * 320);
        const float4* b = (const float4*)(Xm + j * 320);
        float s = 0.f;
        for (int k = 0; k < 80; ++k) {
            float4 va = a[k], vb = b[k];
            s += va.x * vb.x + va.y * vb.y + va.z * vb.z + va.w * vb.w;
        }
        H[idx] = (i == j) ? s + EPS_C : s;
    } else {
        idx -= 102400;
        if (idx < 65536) {
            int i = idx >> 8, j = idx & 255;
            const float4* a = (const float4*)(XPm + i * 256);
            const float4* b = (const float4*)(XPm + j * 256);
            float s = 0.f;
            for (int k = 0; k < 64; ++k) {
                float4 va = a[k], vb = b[k];
                s += va.x * vb.x + va.y * vb.y + va.z * vb.z + va.w * vb.w;
            }
            P[idx] = (i == j) ? s + EPS_C : s;
        }
    }
}

// ---------------- setup: derived small matrices ----------------
__global__ void k_derived(const float* __restrict__ H, const float* __restrict__ Um,
                          const float* __restrict__ Y1, const float* __restrict__ B2,
                          float* __restrict__ Y, float* __restrict__ RHS,
                          float* __restrict__ C1T, float* __restrict__ D11g,
                          float* __restrict__ Wf) {
    int idx = blockIdx.x * 256 + threadIdx.x;
    if (idx < 65536) {
        int i = idx >> 8, j = idx & 255;
        Y[idx] = -0.5f * (H[i * 320 + j] + Y1[i * 256 + j] - Y1[j * 256 + i]);
        return;
    }
    idx -= 65536;
    if (idx < 16384) { // RHS = -H12 - U
        RHS[idx] = -H[(idx >> 6) * 320 + 256 + (idx & 63)] - Um[idx];
        return;
    }
    idx -= 16384;
    if (idx < 16384) { // C1T[d][q] = U[d][q]/lam[q]
        int q = idx & 63;
        float lam = 0.5f * H[(256 + q) * 320 + 256 + q];
        C1T[idx] = Um[idx] / lam;
        return;
    }
    idx -= 16384;
    if (idx < 4096) { // D11[q][j]
        int q = idx >> 6, j = idx & 63;
        float lam = 0.5f * H[(256 + q) * 320 + 256 + q];
        D11g[idx] = (j < q) ? -H[(256 + q) * 320 + 256 + j] / lam : 0.f;
        return;
    }
    idx -= 4096;
    if (idx < 2048) { // Wf tail: B2 at cols 320..327
        int o = idx >> 3, k = idx & 7;
        Wf[(size_t)o * 328 + 320 + k] = B2[idx];
    }
}

// ---------------- GJ step 1: E = inv(A_bb) via in-LDS scalar Gauss-Jordan ----------------
// 256 threads; thread owns M[row][seg*16 .. seg*16+15], row=tid>>2, seg=tid&3. No big register arrays.
__global__ void __launch_bounds__(256) k_inv64(float* __restrict__ C, float* __restrict__ E, int b) {
    __shared__ float M[64 * 65];
    const int tid = threadIdx.x;
    const int row = tid >> 2, seg = tid & 3;
    const int c0 = seg * 16;
    {
        const float* src = C + (size_t)(b * 64 + row) * 256 + b * 64 + c0;
#pragma unroll
        for (int t = 0; t < 4; ++t) {
            float4 v = *(const float4*)(src + t * 4);
            M[row * 65 + c0 + t * 4 + 0] = v.x;
            M[row * 65 + c0 + t * 4 + 1] = v.y;
            M[row * 65 + c0 + t * 4 + 2] = v.z;
            M[row * 65 + c0 + t * 4 + 3] = v.w;
        }
    }
    for (int k = 0; k < 64; ++k) {
        __syncthreads();
        const float p = M[k * 65 + k];
        const float rinv = 1.0f / p;
        const float pk = M[row * 65 + k];
        float mk[16];
#pragma unroll
        for (int t = 0; t < 16; ++t) mk[t] = M[k * 65 + c0 + t];
        __syncthreads();
        if (row == k) {
#pragma unroll
            for (int t = 0; t < 16; ++t) {
                const int col = c0 + t;
                M[k * 65 + col] = (col == k) ? rinv : mk[t] * rinv;
            }
        } else {
            const float f = -pk * rinv;
#pragma unroll
            for (int t = 0; t < 16; ++t) {
                const int col = c0 + t;
                M[row * 65 + col] = (col == k) ? f : fmaf(f, mk[t], M[row * 65 + col]);
            }
        }
    }
    __syncthreads();
    {
        float* dstE = E + (size_t)row * 64 + c0;
        float* dstC = C + (size_t)(b * 64 + row) * 256 + b * 64 + c0;
#pragma unroll
        for (int t = 0; t < 4; ++t) {
            float4 v = {M[row * 65 + c0 + t * 4 + 0], M[row * 65 + c0 + t * 4 + 1],
                        M[row * 65 + c0 + t * 4 + 2], M[row * 65 + c0 + t * 4 + 3]};
            *(float4*)(dstE + t * 4) = v;
            *(float4*)(dstC + t * 4) = v;
        }
    }
}

// ---------------- GJ step 2: T = A[:,b]*E ; W = E*A[b,:] ; R = copy A[b,:] ----------------
// blocks 0..3: T tile I ; blocks 4..7: W tile J + R copy
__global__ void __launch_bounds__(256) k_gjT(const float* __restrict__ C, const float* __restrict__ E,
                                             float* __restrict__ T, float* __restrict__ R,
                                             float* __restrict__ W, int b) {
    __shared__ __align__(16) float As[64 * 68];
    __shared__ __align__(16) float Es[64 * 68];
    const int tid = threadIdx.x;
    const int ti = tid & 15, tj = tid >> 4;
    const bool isT = blockIdx.x < 4;
    const int blk = isT ? blockIdx.x : blockIdx.x - 4;
    // load E
    for (int e = tid; e < 1024; e += 256) {
        int r = e >> 4, c4 = e & 15;
        float4 v = *(const float4*)&E[(size_t)r * 64 + c4 * 4];
        *(float4*)&Es[r * 68 + c4 * 4] = v;
    }
    // load A tile
    for (int e = tid; e < 1024; e += 256) {
        int r = e >> 4, c4 = e & 15;
        float4 v;
        if (isT) v = *(const float4*)&C[(size_t)(blk * 64 + r) * 256 + b * 64 + c4 * 4];
        else {
            v = *(const float4*)&C[(size_t)(b * 64 + r) * 256 + blk * 64 + c4 * 4];
            *(float4*)&R[(size_t)r * 256 + blk * 64 + c4 * 4] = v; // R copy
        }
        *(float4*)&As[r * 68 + c4 * 4] = v;
    }
    __syncthreads();
    float acc[4][4];
#pragma unroll
    for (int r = 0; r < 4; ++r)
#pragma unroll
        for (int d = 0; d < 4; ++d) acc[r][d] = 0.f;
    if (isT) { // T[i][j] = sum_k As[i][k]*Es[k][j]
        for (int kk = 0; kk < 64; ++kk) {
            float a4[4], b4[4];
#pragma unroll
            for (int d = 0; d < 4; ++d) { a4[d] = As[(ti * 4 + d) * 68 + kk]; b4[d] = Es[kk * 68 + tj * 4 + d]; }
#pragma unroll
            for (int r = 0; r < 4; ++r)
#pragma unroll
                for (int d = 0; d < 4; ++d) acc[r][d] = fmaf(a4[r], b4[d], acc[r][d]);
        }
#pragma unroll
        for (int r = 0; r < 4; ++r) {
            float4 v = {acc[r][0], acc[r][1], acc[r][2], acc[r][3]};
            *(float4*)&T[(size_t)(blk * 64 + ti * 4 + r) * 64 + tj * 4] = v;
        }
    } else { // W[k][j] = sum_m Es[k][m]*As[m][j]
        for (int mm = 0; mm < 64; ++mm) {
            float a4[4], b4[4];
#pragma unroll
            for (int d = 0; d < 4; ++d) { a4[d] = Es[(ti * 4 + d) * 68 + mm]; b4[d] = As[mm * 68 + tj * 4 + d]; }
#pragma unroll
            for (int r = 0; r < 4; ++r)
#pragma unroll
                for (int d = 0; d < 4; ++d) acc[r][d] = fmaf(a4[r], b4[d], acc[r][d]);
        }
#pragma unroll
        for (int r = 0; r < 4; ++r) {
            float4 v = {acc[r][0], acc[r][1], acc[r][2], acc[r][3]};
            *(float4*)&W[(size_t)(ti * 4 + r) * 256 + blk * 64 + tj * 4] = v;
        }
    }
}

// ---------------- GJ step 3: apply update ----------------
// tile (I,J): I==J==b: skip (done) | I==b: A=W | J==b: A=-T | else A -= T_I * R_J
__global__ void __launch_bounds__(256) k_gjU(float* __restrict__ C, const float* __restrict__ T,
                                             const float* __restrict__ R, const float* __restrict__ W,
                                             int b) {
    const int I = blockIdx.x >> 2, J = blockIdx.x & 3;
    const int tid = threadIdx.x;
    if (I == b && J == b) return;
    if (I == b) { // row block <- W
        const int r = tid >> 2, seg = tid & 3;
#pragma unroll
        for (int t = 0; t < 4; ++t) {
            float4 v = *(const float4*)&W[(size_t)r * 256 + J * 64 + seg * 16 + t * 4];
            *(float4*)&C[(size_t)(b * 64 + r) * 256 + J * 64 + seg * 16 + t * 4] = v;
        }
        return;
    }
    if (J == b) { // col block <- -T
        const int r = tid >> 2, seg = tid & 3;
#pragma unroll
        for (int t = 0; t < 4; ++t) {
            float4 v = *(const float4*)&T[(size_t)(I * 64 + r) * 64 + seg * 16 + t * 4];
            float4 nv = {-v.x, -v.y, -v.z, -v.w};
            *(float4*)&C[(size_t)(I * 64 + r) * 256 + b * 64 + seg * 16 + t * 4] = nv;
        }
        return;
    }
    __shared__ __align__(16) float Ts[64 * 68];
    __shared__ __align__(16) float Rs[64 * 68];
    for (int e = tid; e < 1024; e += 256) {
        int r = e >> 4, c4 = e & 15;
        float4 v = *(const float4*)&T[(size_t)(I * 64 + r) * 64 + c4 * 4];
        *(float4*)&Ts[r * 68 + c4 * 4] = v;
        float4 w = *(const float4*)&R[(size_t)r * 256 + J * 64 + c4 * 4];
        *(float4*)&Rs[r * 68 + c4 * 4] = w;
    }
    __syncthreads();
    const int ti = tid & 15, tj = tid >> 4;
    float acc[4][4];
#pragma unroll
    for (int r = 0; r < 4; ++r) {
        float4 cv = *(const float4*)&C[(size_t)(I * 64 + ti * 4 + r) * 256 + J * 64 + tj * 4];
        acc[r][0] = cv.x; acc[r][1] = cv.y; acc[r][2] = cv.z; acc[r][3] = cv.w;
    }
    for (int kk = 0; kk < 64; ++kk) {
        float a4[4], b4[4];
#pragma unroll
        for (int d = 0; d < 4; ++d) { a4[d] = Ts[(ti * 4 + d) * 68 + kk]; b4[d] = Rs[kk * 68 + tj * 4 + d]; }
#pragma unroll
        for (int r = 0; r < 4; ++r)
#pragma unroll
            for (int d = 0; d < 4; ++d) acc[r][d] = fmaf(-a4[r], b4[d], acc[r][d]);
    }
#pragma unroll
    for (int r = 0; r < 4; ++r) {
        float4 v = {acc[r][0], acc[r][1], acc[r][2], acc[r][3]};
        *(float4*)&C[(size_t)(I * 64 + ti * 4 + r) * 256 + J * 64 + tj * 4] = v;
    }
}

// ---------------- Wf[:,0:320] = PI @ [Y | RHS] ----------------
__global__ void __launch_bounds__(256) k_apply(const float* __restrict__ PI, const float* __restrict__ Y,
                                               const float* __restrict__ RHS, float* __restrict__ Wf) {
    const int i0 = (blockIdx.x / 5) * 64;
    const int c0 = (blockIdx.x % 5) * 64;
    __shared__ __align__(16) float Ps[64 * 68], Gs[64 * 68];
    const int tid = threadIdx.x;
    const int ti = tid & 15, tj = tid >> 4;
    float acc[4][4];
#pragma unroll
    for (int r = 0; r < 4; ++r)
#pragma unroll
        for (int d = 0; d < 4; ++d) acc[r][d] = 0.f;
    for (int kc = 0; kc < 4; ++kc) {
        __syncthreads();
        for (int e = tid; e < 1024; e += 256) {
            int i = e >> 4, k4 = e & 15;
            float4 v = *(const float4*)&PI[(size_t)(i0 + i) * 256 + kc * 64 + k4 * 4];
            Ps[(k4 * 4 + 0) * 68 + i] = v.x;
            Ps[(k4 * 4 + 1) * 68 + i] = v.y;
            Ps[(k4 * 4 + 2) * 68 + i] = v.z;
            Ps[(k4 * 4 + 3) * 68 + i] = v.w;
            float4 w;
            if (c0 < 256) w = *(const float4*)&Y[(size_t)(kc * 64 + i) * 256 + c0 + k4 * 4];
            else          w = *(const float4*)&RHS[(size_t)(kc * 64 + i) * 64 + k4 * 4];
            *(float4*)&Gs[i * 68 + k4 * 4] = w;
        }
        __syncthreads();
        for (int kk = 0; kk < 64; ++kk) {
            float4 pv = *(const float4*)&Ps[kk * 68 + ti * 4];
            float4 gv = *(const float4*)&Gs[kk * 68 + tj * 4];
            float p4[4] = {pv.x, pv.y, pv.z, pv.w};
            float g4[4] = {gv.x, gv.y, gv.z, gv.w};
#pragma unroll
            for (int r = 0; r < 4; ++r)
#pragma unroll
                for (int d = 0; d < 4; ++d) acc[r][d] = fmaf(p4[r], g4[d], acc[r][d]);
        }
    }
#pragma unroll
    for (int r = 0; r < 4; ++r) {
        float4 v = {acc[r][0], acc[r][1], acc[r][2], acc[r][3]};
        *(float4*)&Wf[(size_t)(i0 + ti * 4 + r) * 328 + c0 + tj * 4] = v;
    }
}

// ---------------- pack Wf -> 3-way bf16 split, layout [A | B2 | 0 | B1], K=352 ----------------
__global__ void k_packWf3(const float* __restrict__ Wf, unsigned short* __restrict__ Bh,
                          unsigned short* __restrict__ Bm, unsigned short* __restrict__ Bl) {
    int idx = blockIdx.x * 256 + threadIdx.x; // 256*352 = 90112
    if (idx >= 90112) return;
    int n = idx / 352, k = idx - n * 352;
    float f;
    if (k < 256)      f = Wf[(size_t)n * 328 + k];               // A
    else if (k < 264) f = Wf[(size_t)n * 328 + 320 + (k - 256)]; // B2
    else if (k < 288) f = 0.f;                                    // pad
    else              f = Wf[(size_t)n * 328 + 256 + (k - 288)]; // B1
    unsigned short h = f2bf(f);
    float r1 = f - bf2f(h);
    unsigned short m = f2bf(r1);
    float r2 = r1 - bf2f(m);
    unsigned short l = f2bf(r2);
    Bh[idx] = h; Bm[idx] = m; Bl[idx] = l;
}

// ---------------- main 1: base + recurrence -> w (fp32) ----------------
__global__ void __launch_bounds__(256) k_m1(const float* __restrict__ x, const float* __restrict__ u,
                                            const float* __restrict__ C1T, const float* __restrict__ D12,
                                            const float* __restrict__ bv, const float* __restrict__ D11g,
                                            float* __restrict__ wg) {
    __shared__ __align__(16) float sbuf[32 * 257];
    __shared__ float us[256 * 9];
    const int tid = threadIdx.x;
    const int r0 = blockIdx.x * 256;
#pragma unroll
    for (int i = 0; i < 8; ++i) {
        int e = tid + i * 256, r = e >> 3, j = e & 7;
        us[r * 9 + j] = u[(size_t)(r0 + r) * 8 + j];
    }
    float w[64];
#pragma unroll
    for (int q = 0; q < 64; ++q) w[q] = bv[q];
    const float4* xg4 = (const float4*)x;
    for (int kc = 0; kc < 8; ++kc) {
        __syncthreads();
#pragma unroll
        for (int i = 0; i < 8; ++i) {
            int e = tid + i * 256, r = e >> 3, c4 = e & 7;
            float4 v = xg4[(size_t)(r0 + r) * 64 + kc * 8 + c4];
            sbuf[(c4 * 4 + 0) * 257 + r] = v.x;
            sbuf[(c4 * 4 + 1) * 257 + r] = v.y;
            sbuf[(c4 * 4 + 2) * 257 + r] = v.z;
            sbuf[(c4 * 4 + 3) * 257 + r] = v.w;
        }
        __syncthreads();
        const float* c1p = C1T + kc * 32 * 64;
#pragma unroll 4
        for (int k = 0; k < 32; ++k) {
            float xv = sbuf[k * 257 + tid];
#pragma unroll
            for (int q = 0; q < 64; ++q) w[q] = fmaf(xv, c1p[k * 64 + q], w[q]);
        }
    }
#pragma unroll
    for (int j = 0; j < 8; ++j) {
        float uv = us[tid * 9 + j];
#pragma unroll
        for (int q = 0; q < 64; ++q) w[q] = fmaf(uv, D12[q * 8 + j], w[q]);
    }
    w[0] = fmaxf(w[0], 0.f);
#pragma unroll
    for (int i = 1; i < 64; ++i) {
        float s = w[i];
#pragma unroll
        for (int j = 0; j < i; ++j) s = fmaf(w[j], D11g[i * 64 + j], s);
        w[i] = fmaxf(s, 0.f);
    }
    float* wr = wg + (size_t)(r0 + tid) * 64;
#pragma unroll
    for (int c = 0; c < 16; ++c) {
        float4 v = {w[4 * c], w[4 * c + 1], w[4 * c + 2], w[4 * c + 3]};
        *(float4*)&wr[c * 4] = v;
    }
}

// ---------------- main 2: out = [x|u|0|w] @ WfP^T via tiered bf16x3-split MFMA ----------------
#define ASTR 360
__global__ void __launch_bounds__(256) k_m2(const float* __restrict__ x, const float* __restrict__ wg,
                                            const float* __restrict__ u,
                                            const unsigned short* __restrict__ Bh,
                                            const unsigned short* __restrict__ Bm,
                                            const unsigned short* __restrict__ Bl,
                                            float* __restrict__ out) {
    __shared__ __align__(16) unsigned short Ah[32 * ASTR];
    __shared__ __align__(16) unsigned short Am[32 * ASTR];
    __shared__ __align__(16) unsigned short Al[32 * ASTR];
    const int tid = threadIdx.x;
    const int r0 = blockIdx.x * 32;
    {
        const float4* xg4 = (const float4*)(x + (size_t)r0 * 256);
#pragma unroll
        for (int i = 0; i < 8; ++i) {
            int e = tid + i * 256, r = e >> 6, c4 = e & 63;
            float4 v = xg4[e];
            float vv[4] = {v.x, v.y, v.z, v.w};
            u16x4 hv, mv, lv;
#pragma unroll
            for (int j = 0; j < 4; ++j) {
                unsigned short h = f2bf(vv[j]);
                float rr1 = vv[j] - bf2f(h);
                unsigned short m = f2bf(rr1);
                lv[j] = f2bf(rr1 - bf2f(m));
                hv[j] = h; mv[j] = m;
            }
            *(u16x4*)&Ah[r * ASTR + c4 * 4] = hv;
            *(u16x4*)&Am[r * ASTR + c4 * 4] = mv;
            *(u16x4*)&Al[r * ASTR + c4 * 4] = lv;
        }
    }
    if (tid < 64) {
        int r = tid >> 1, h4 = tid & 1;
        float4 v = *(const float4*)&u[(size_t)(r0 + r) * 8 + h4 * 4];
        float vv[4] = {v.x, v.y, v.z, v.w};
        u16x4 hv, mv, lv;
#pragma unroll
        for (int j = 0; j < 4; ++j) {
            unsigned short h = f2bf(vv[j]);
            float rr1 = vv[j] - bf2f(h);
            unsigned short m = f2bf(rr1);
            lv[j] = f2bf(rr1 - bf2f(m));
            hv[j] = h; mv[j] = m;
        }
        *(u16x4*)&Ah[r * ASTR + 256 + h4 * 4] = hv;
        *(u16x4*)&Am[r * ASTR + 256 + h4 * 4] = mv;
        *(u16x4*)&Al[r * ASTR + 256 + h4 * 4] = lv;
    }
    if (tid < 96) {
        int r = tid / 3, cc = tid - r * 3;
        u16x8 z = {0, 0, 0, 0, 0, 0, 0, 0};
        *(u16x8*)&Ah[r * ASTR + 264 + cc * 8] = z;
        *(u16x8*)&Am[r * ASTR + 264 + cc * 8] = z;
        *(u16x8*)&Al[r * ASTR + 264 + cc * 8] = z;
    }
    {
        int r = tid >> 3, c8 = tid & 7;
        const float4* wp = (const float4*)&wg[(size_t)(r0 + r) * 64 + c8 * 8];
        float4 v0 = wp[0], v1 = wp[1];
        float vv[8] = {v0.x, v0.y, v0.z, v0.w, v1.x, v1.y, v1.z, v1.w};
        u16x8 hv, mv, lv;
#pragma unroll
        for (int j = 0; j < 8; ++j) {
            unsigned short h = f2bf(vv[j]);
            float rr1 = vv[j] - bf2f(h);
            unsigned short m = f2bf(rr1);
            lv[j] = f2bf(rr1 - bf2f(m));
            hv[j] = h; mv[j] = m;
        }
        *(u16x8*)&Ah[r * ASTR + 288 + c8 * 8] = hv;
        *(u16x8*)&Am[r * ASTR + 288 + c8 * 8] = mv;
        *(u16x8*)&Al[r * ASTR + 288 + c8 * 8] = lv;
    }
    __syncthreads();

    const int lane = tid & 63, wid = tid >> 6;
    const int n0 = wid * 64;
    const int lr = lane & 15, lg = lane >> 4;
    const int lk = lg * 8;
    f32x4 acc[2][4];
#pragma unroll
    for (int m = 0; m < 2; ++m)
#pragma unroll
        for (int nf = 0; nf < 4; ++nf) acc[m][nf] = (f32x4){0.f, 0.f, 0.f, 0.f};

    for (int kt = 0; kt < 11; ++kt) {
        const int ka = kt * 32 + lk;
        short8 a_h[2], a_m[2], a_l[2];
        a_h[0] = *(const short8*)&Ah[lr * ASTR + ka];
        a_h[1] = *(const short8*)&Ah[(16 + lr) * ASTR + ka];
        a_m[0] = *(const short8*)&Am[lr * ASTR + ka];
        a_m[1] = *(const short8*)&Am[(16 + lr) * ASTR + ka];
        a_l[0] = *(const short8*)&Al[lr * ASTR + ka];
        a_l[1] = *(const short8*)&Al[(16 + lr) * ASTR + ka];
        short8 b_h[4], b_m[4], b_l[4];
#pragma unroll
        for (int nf = 0; nf < 4; ++nf) {
            const size_t n = (size_t)(n0 + nf * 16 + lr);
            b_h[nf] = *(const short8*)&Bh[n * 352 + ka];
            b_m[nf] = *(const short8*)&Bm[n * 352 + ka];
            b_l[nf] = *(const short8*)&Bl[n * 352 + ka];
        }
        const bool wtile = (kt >= 9);
#pragma unroll
        for (int m = 0; m < 2; ++m)
#pragma unroll
            for (int nf = 0; nf < 4; ++nf) {
                acc[m][nf] = __builtin_amdgcn_mfma_f32_16x16x32_bf16(a_h[m], b_h[nf], acc[m][nf], 0, 0, 0);
                acc[m][nf] = __builtin_amdgcn_mfma_f32_16x16x32_bf16(a_m[m], b_h[nf], acc[m][nf], 0, 0, 0);
                acc[m][nf] = __builtin_amdgcn_mfma_f32_16x16x32_bf16(a_h[m], b_m[nf], acc[m][nf], 0, 0, 0);
                acc[m][nf] = __builtin_amdgcn_mfma_f32_16x16x32_bf16(a_l[m], b_h[nf], acc[m][nf], 0, 0, 0);
                acc[m][nf] = __builtin_amdgcn_mfma_f32_16x16x32_bf16(a_m[m], b_m[nf], acc[m][nf], 0, 0, 0);
                acc[m][nf] = __builtin_amdgcn_mfma_f32_16x16x32_bf16(a_h[m], b_l[nf], acc[m][nf], 0, 0, 0);
                if (wtile) {
                    acc[m][nf] = __builtin_amdgcn_mfma_f32_16x16x32_bf16(a_m[m], b_l[nf], acc[m][nf], 0, 0, 0);
                    acc[m][nf] = __builtin_amdgcn_mfma_f32_16x16x32_bf16(a_l[m], b_m[nf], acc[m][nf], 0, 0, 0);
                }
            }
    }
#pragma unroll
    for (int m = 0; m < 2; ++m)
#pragma unroll
        for (int nf = 0; nf < 4; ++nf)
#pragma unroll
            for (int j = 0; j < 4; ++j)
                out[(size_t)(r0 + m * 16 + lg * 4 + j) * 256 + n0 + nf * 16 + lr] = acc[m][nf][j];
}

extern "C" void kernel_launch(void* const* d_in, const int* in_sizes, int n_in,
                              void* d_out, int out_size, void* d_ws, size_t ws_size,
                              hipStream_t stream) {
    const float* x   = (const float*)d_in[0];
    const float* u   = (const float*)d_in[1];
    const float* Xm  = (const float*)d_in[2];
    const float* Um  = (const float*)d_in[3];
    const float* Y1  = (const float*)d_in[4];
    const float* XPm = (const float*)d_in[5];
    const float* B2  = (const float*)d_in[6];
    const float* D12 = (const float*)d_in[7];
    const float* bv  = (const float*)d_in[8];
    float* out = (float*)d_out;
    float* ws  = (float*)d_ws;

    float* H    = ws + WS_H;
    float* C    = ws + WS_C;
    float* T    = ws + WS_T;
    float* R    = ws + WS_R;
    float* W    = ws + WS_W;
    float* E    = ws + WS_E;
    float* Y    = ws + WS_Y;
    float* RHS  = ws + WS_RHS;
    float* C1T  = ws + WS_C1T;
    float* D11g = ws + WS_D11;
    float* Wf   = ws + WS_WF;
    unsigned short* Bh = (unsigned short*)(ws + WS_WFH);
    unsigned short* Bm = (unsigned short*)(ws + WS_WFM);
    unsigned short* Bl = (unsigned short*)(ws + WS_WFL);
    float* wg = ws + WS_WG;

    k_build<<<656, 256, 0, stream>>>(Xm, XPm, H, C);
    k_derived<<<408, 256, 0, stream>>>(H, Um, Y1, B2, Y, RHS, C1T, D11g, Wf);
    k_m1<<<256, 256, 0, stream>>>(x, u, C1T, D12, bv, D11g, wg);
    for (int b = 0; b < 4; ++b) {
        k_inv64<<<1, 256, 0, stream>>>(C, E, b);
        k_gjT<<<8, 256, 0, stream>>>(C, E, T, R, W, b);
        k_gjU<<<16, 256, 0, stream>>>(C, T, R, W, b);
    }
    k_apply<<<20, 256, 0, stream>>>(C, Y, RHS, Wf);
    k_packWf3<<<352, 256, 0, stream>>>(Wf, Bh, Bm, Bl);
    k_m2<<<2048, 256, 0, stream>>>(x, wg, u, Bh, Bm, Bl, out);
}

// Round 7
// 523.570 us; speedup vs baseline: 2.0046x; 1.1654x over previous
//
#include <hip/hip_runtime.h>

#define EPS_C 0.01f

typedef __attribute__((ext_vector_type(8))) short short8;
typedef __attribute__((ext_vector_type(4))) float f32x4;
typedef __attribute__((ext_vector_type(4))) unsigned short u16x4;
typedef __attribute__((ext_vector_type(8))) unsigned short u16x8;

// ---------- workspace layout (float offsets) ----------
#define WS_H    0        // 320*320
#define WS_C    102400   // 256*256  P -> (block GJ) -> Pinv, in place
#define WS_T    167936   // 256*64   T = A[:,b] * E
#define WS_R    184320   // 64*256   R = old A[b,:]
#define WS_W    200704   // 64*256   W = E * A[b,:]
#define WS_E    217088   // 64*64    E = inv(A_bb)
#define WS_Y    233472   // 256*256
#define WS_RHS  299008   // 256*64
#define WS_C1T  315392   // 256*64
#define WS_D11  331776   // 64*64
#define WS_WF   335872   // 256*328 fp32  [A | B1 | B2]
#define WS_WFH  419840   // 256*352 u16 each
#define WS_WFM  464896
#define WS_WFL  509952
#define WS_BBH  555008   // 64*288 u16 each (base B = [C1T^T | D12 | 0])
#define WS_BBM  564224
#define WS_BBL  573440
#define WS_WG   582656   // 65536*64 fp32 (base, then w in place)

__device__ __forceinline__ unsigned short f2bf(float f) {
    unsigned int u = __float_as_uint(f);
    unsigned int r = (u + 0x7fffu + ((u >> 16) & 1u)) >> 16;
    return (unsigned short)r;
}
__device__ __forceinline__ float bf2f(unsigned short h) {
    return __uint_as_float(((unsigned int)h) << 16);
}

// ---------------- setup: P and H builds ----------------
__global__ void k_build(const float* __restrict__ Xm, const float* __restrict__ XPm,
                        float* __restrict__ H, float* __restrict__ P) {
    int idx = blockIdx.x * 256 + threadIdx.x;
    if (idx < 102400) {
        int i = idx / 320, j = idx - i * 320;
        const float4* a = (const float4*)(Xm + i * 320);
        const float4* b = (const float4*)(Xm + j * 320);
        float s = 0.f;
        for (int k = 0; k < 80; ++k) {
            float4 va = a[k], vb = b[k];
            s += va.x * vb.x + va.y * vb.y + va.z * vb.z + va.w * vb.w;
        }
        H[idx] = (i == j) ? s + EPS_C : s;
    } else {
        idx -= 102400;
        if (idx < 65536) {
            int i = idx >> 8, j = idx & 255;
            const float4* a = (const float4*)(XPm + i * 256);
            const float4* b = (const float4*)(XPm + j * 256);
            float s = 0.f;
            for (int k = 0; k < 64; ++k) {
                float4 va = a[k], vb = b[k];
                s += va.x * vb.x + va.y * vb.y + va.z * vb.z + va.w * vb.w;
            }
            P[idx] = (i == j) ? s + EPS_C : s;
        }
    }
}

// ---------------- setup: derived small matrices ----------------
__global__ void k_derived(const float* __restrict__ H, const float* __restrict__ Um,
                          const float* __restrict__ Y1, const float* __restrict__ B2,
                          float* __restrict__ Y, float* __restrict__ RHS,
                          float* __restrict__ C1T, float* __restrict__ D11g,
                          float* __restrict__ Wf) {
    int idx = blockIdx.x * 256 + threadIdx.x;
    if (idx < 65536) {
        int i = idx >> 8, j = idx & 255;
        Y[idx] = -0.5f * (H[i * 320 + j] + Y1[i * 256 + j] - Y1[j * 256 + i]);
        return;
    }
    idx -= 65536;
    if (idx < 16384) { // RHS = -H12 - U
        RHS[idx] = -H[(idx >> 6) * 320 + 256 + (idx & 63)] - Um[idx];
        return;
    }
    idx -= 16384;
    if (idx < 16384) { // C1T[d][q] = U[d][q]/lam[q]
        int q = idx & 63;
        float lam = 0.5f * H[(256 + q) * 320 + 256 + q];
        C1T[idx] = Um[idx] / lam;
        return;
    }
    idx -= 16384;
    if (idx < 4096) { // D11[q][j]
        int q = idx >> 6, j = idx & 63;
        float lam = 0.5f * H[(256 + q) * 320 + 256 + q];
        D11g[idx] = (j < q) ? -H[(256 + q) * 320 + 256 + j] / lam : 0.f;
        return;
    }
    idx -= 4096;
    if (idx < 2048) { // Wf tail: B2 at cols 320..327
        int o = idx >> 3, k = idx & 7;
        Wf[(size_t)o * 328 + 320 + k] = B2[idx];
    }
}

// ---------------- pack Bb = [C1T^T | D12 | 0] (64 x 288), 3-way bf16 ----------------
__global__ void k_packBb(const float* __restrict__ C1T, const float* __restrict__ D12,
                         unsigned short* __restrict__ Bbh, unsigned short* __restrict__ Bbm,
                         unsigned short* __restrict__ Bbl) {
    int idx = blockIdx.x * 256 + threadIdx.x; // 64*288 = 18432
    if (idx >= 18432) return;
    int q = idx / 288, k = idx - q * 288;
    float f;
    if (k < 256)      f = C1T[(size_t)k * 64 + q];
    else if (k < 264) f = D12[(size_t)q * 8 + (k - 256)];
    else              f = 0.f;
    unsigned short h = f2bf(f);
    float r1 = f - bf2f(h);
    unsigned short m = f2bf(r1);
    float r2 = r1 - bf2f(m);
    unsigned short l = f2bf(r2);
    Bbh[idx] = h; Bbm[idx] = m; Bbl[idx] = l;
}

// ---------------- GJ step 1: E = inv(A_bb) via in-LDS scalar Gauss-Jordan ----------------
__global__ void __launch_bounds__(256) k_inv64(float* __restrict__ C, float* __restrict__ E, int b) {
    __shared__ float M[64 * 65];
    const int tid = threadIdx.x;
    const int row = tid >> 2, seg = tid & 3;
    const int c0 = seg * 16;
    {
        const float* src = C + (size_t)(b * 64 + row) * 256 + b * 64 + c0;
#pragma unroll
        for (int t = 0; t < 4; ++t) {
            float4 v = *(const float4*)(src + t * 4);
            M[row * 65 + c0 + t * 4 + 0] = v.x;
            M[row * 65 + c0 + t * 4 + 1] = v.y;
            M[row * 65 + c0 + t * 4 + 2] = v.z;
            M[row * 65 + c0 + t * 4 + 3] = v.w;
        }
    }
    for (int k = 0; k < 64; ++k) {
        __syncthreads();
        const float p = M[k * 65 + k];
        const float rinv = 1.0f / p;
        const float pk = M[row * 65 + k];
        float mk[16];
#pragma unroll
        for (int t = 0; t < 16; ++t) mk[t] = M[k * 65 + c0 + t];
        __syncthreads();
        if (row == k) {
#pragma unroll
            for (int t = 0; t < 16; ++t) {
                const int col = c0 + t;
                M[k * 65 + col] = (col == k) ? rinv : mk[t] * rinv;
            }
        } else {
            const float f = -pk * rinv;
#pragma unroll
            for (int t = 0; t < 16; ++t) {
                const int col = c0 + t;
                M[row * 65 + col] = (col == k) ? f : fmaf(f, mk[t], M[row * 65 + col]);
            }
        }
    }
    __syncthreads();
    {
        float* dstE = E + (size_t)row * 64 + c0;
        float* dstC = C + (size_t)(b * 64 + row) * 256 + b * 64 + c0;
#pragma unroll
        for (int t = 0; t < 4; ++t) {
            float4 v = {M[row * 65 + c0 + t * 4 + 0], M[row * 65 + c0 + t * 4 + 1],
                        M[row * 65 + c0 + t * 4 + 2], M[row * 65 + c0 + t * 4 + 3]};
            *(float4*)(dstE + t * 4) = v;
            *(float4*)(dstC + t * 4) = v;
        }
    }
}

// ---------------- GJ step 2: T = A[:,b]*E ; W = E*A[b,:] ; R = copy A[b,:] ----------------
__global__ void __launch_bounds__(256) k_gjT(const float* __restrict__ C, const float* __restrict__ E,
                                             float* __restrict__ T, float* __restrict__ R,
                                             float* __restrict__ W, int b) {
    __shared__ __align__(16) float As[64 * 68];
    __shared__ __align__(16) float Es[64 * 68];
    const int tid = threadIdx.x;
    const int ti = tid & 15, tj = tid >> 4;
    const bool isT = blockIdx.x < 4;
    const int blk = isT ? blockIdx.x : blockIdx.x - 4;
    for (int e = tid; e < 1024; e += 256) {
        int r = e >> 4, c4 = e & 15;
        float4 v = *(const float4*)&E[(size_t)r * 64 + c4 * 4];
        *(float4*)&Es[r * 68 + c4 * 4] = v;
    }
    for (int e = tid; e < 1024; e += 256) {
        int r = e >> 4, c4 = e & 15;
        float4 v;
        if (isT) v = *(const float4*)&C[(size_t)(blk * 64 + r) * 256 + b * 64 + c4 * 4];
        else {
            v = *(const float4*)&C[(size_t)(b * 64 + r) * 256 + blk * 64 + c4 * 4];
            *(float4*)&R[(size_t)r * 256 + blk * 64 + c4 * 4] = v;
        }
        *(float4*)&As[r * 68 + c4 * 4] = v;
    }
    __syncthreads();
    float acc[4][4];
#pragma unroll
    for (int r = 0; r < 4; ++r)
#pragma unroll
        for (int d = 0; d < 4; ++d) acc[r][d] = 0.f;
    if (isT) {
        for (int kk = 0; kk < 64; ++kk) {
            float a4[4], b4[4];
#pragma unroll
            for (int d = 0; d < 4; ++d) { a4[d] = As[(ti * 4 + d) * 68 + kk]; b4[d] = Es[kk * 68 + tj * 4 + d]; }
#pragma unroll
            for (int r = 0; r < 4; ++r)
#pragma unroll
                for (int d = 0; d < 4; ++d) acc[r][d] = fmaf(a4[r], b4[d], acc[r][d]);
        }
#pragma unroll
        for (int r = 0; r < 4; ++r) {
            float4 v = {acc[r][0], acc[r][1], acc[r][2], acc[r][3]};
            *(float4*)&T[(size_t)(blk * 64 + ti * 4 + r) * 64 + tj * 4] = v;
        }
    } else {
        for (int mm = 0; mm < 64; ++mm) {
            float a4[4], b4[4];
#pragma unroll
            for (int d = 0; d < 4; ++d) { a4[d] = Es[(ti * 4 + d) * 68 + mm]; b4[d] = As[mm * 68 + tj * 4 + d]; }
#pragma unroll
            for (int r = 0; r < 4; ++r)
#pragma unroll
                for (int d = 0; d < 4; ++d) acc[r][d] = fmaf(a4[r], b4[d], acc[r][d]);
        }
#pragma unroll
        for (int r = 0; r < 4; ++r) {
            float4 v = {acc[r][0], acc[r][1], acc[r][2], acc[r][3]};
            *(float4*)&W[(size_t)(ti * 4 + r) * 256 + blk * 64 + tj * 4] = v;
        }
    }
}

// ---------------- GJ step 3: apply update ----------------
__global__ void __launch_bounds__(256) k_gjU(float* __restrict__ C, const float* __restrict__ T,
                                             const float* __restrict__ R, const float* __restrict__ W,
                                             int b) {
    const int I = blockIdx.x >> 2, J = blockIdx.x & 3;
    const int tid = threadIdx.x;
    if (I == b && J == b) return;
    if (I == b) {
        const int r = tid >> 2, seg = tid & 3;
#pragma unroll
        for (int t = 0; t < 4; ++t) {
            float4 v = *(const float4*)&W[(size_t)r * 256 + J * 64 + seg * 16 + t * 4];
            *(float4*)&C[(size_t)(b * 64 + r) * 256 + J * 64 + seg * 16 + t * 4] = v;
        }
        return;
    }
    if (J == b) {
        const int r = tid >> 2, seg = tid & 3;
#pragma unroll
        for (int t = 0; t < 4; ++t) {
            float4 v = *(const float4*)&T[(size_t)(I * 64 + r) * 64 + seg * 16 + t * 4];
            float4 nv = {-v.x, -v.y, -v.z, -v.w};
            *(float4*)&C[(size_t)(I * 64 + r) * 256 + b * 64 + seg * 16 + t * 4] = nv;
        }
        return;
    }
    __shared__ __align__(16) float Ts[64 * 68];
    __shared__ __align__(16) float Rs[64 * 68];
    for (int e = tid; e < 1024; e += 256) {
        int r = e >> 4, c4 = e & 15;
        float4 v = *(const float4*)&T[(size_t)(I * 64 + r) * 64 + c4 * 4];
        *(float4*)&Ts[r * 68 + c4 * 4] = v;
        float4 w = *(const float4*)&R[(size_t)r * 256 + J * 64 + c4 * 4];
        *(float4*)&Rs[r * 68 + c4 * 4] = w;
    }
    __syncthreads();
    const int ti = tid & 15, tj = tid >> 4;
    float acc[4][4];
#pragma unroll
    for (int r = 0; r < 4; ++r) {
        float4 cv = *(const float4*)&C[(size_t)(I * 64 + ti * 4 + r) * 256 + J * 64 + tj * 4];
        acc[r][0] = cv.x; acc[r][1] = cv.y; acc[r][2] = cv.z; acc[r][3] = cv.w;
    }
    for (int kk = 0; kk < 64; ++kk) {
        float a4[4], b4[4];
#pragma unroll
        for (int d = 0; d < 4; ++d) { a4[d] = Ts[(ti * 4 + d) * 68 + kk]; b4[d] = Rs[kk * 68 + tj * 4 + d]; }
#pragma unroll
        for (int r = 0; r < 4; ++r)
#pragma unroll
            for (int d = 0; d < 4; ++d) acc[r][d] = fmaf(-a4[r], b4[d], acc[r][d]);
    }
#pragma unroll
    for (int r = 0; r < 4; ++r) {
        float4 v = {acc[r][0], acc[r][1], acc[r][2], acc[r][3]};
        *(float4*)&C[(size_t)(I * 64 + ti * 4 + r) * 256 + J * 64 + tj * 4] = v;
    }
}

// ---------------- Wf[:,0:320] = PI @ [Y | RHS] ----------------
__global__ void __launch_bounds__(256) k_apply(const float* __restrict__ PI, const float* __restrict__ Y,
                                               const float* __restrict__ RHS, float* __restrict__ Wf) {
    const int i0 = (blockIdx.x / 5) * 64;
    const int c0 = (blockIdx.x % 5) * 64;
    __shared__ __align__(16) float Ps[64 * 68], Gs[64 * 68];
    const int tid = threadIdx.x;
    const int ti = tid & 15, tj = tid >> 4;
    float acc[4][4];
#pragma unroll
    for (int r = 0; r < 4; ++r)
#pragma unroll
        for (int d = 0; d < 4; ++d) acc[r][d] = 0.f;
    for (int kc = 0; kc < 4; ++kc) {
        __syncthreads();
        for (int e = tid; e < 1024; e += 256) {
            int i = e >> 4, k4 = e & 15;
            float4 v = *(const float4*)&PI[(size_t)(i0 + i) * 256 + kc * 64 + k4 * 4];
            Ps[(k4 * 4 + 0) * 68 + i] = v.x;
            Ps[(k4 * 4 + 1) * 68 + i] = v.y;
            Ps[(k4 * 4 + 2) * 68 + i] = v.z;
            Ps[(k4 * 4 + 3) * 68 + i] = v.w;
            float4 w;
            if (c0 < 256) w = *(const float4*)&Y[(size_t)(kc * 64 + i) * 256 + c0 + k4 * 4];
            else          w = *(const float4*)&RHS[(size_t)(kc * 64 + i) * 64 + k4 * 4];
            *(float4*)&Gs[i * 68 + k4 * 4] = w;
        }
        __syncthreads();
        for (int kk = 0; kk < 64; ++kk) {
            float4 pv = *(const float4*)&Ps[kk * 68 + ti * 4];
            float4 gv = *(const float4*)&Gs[kk * 68 + tj * 4];
            float p4[4] = {pv.x, pv.y, pv.z, pv.w};
            float g4[4] = {gv.x, gv.y, gv.z, gv.w};
#pragma unroll
            for (int r = 0; r < 4; ++r)
#pragma unroll
                for (int d = 0; d < 4; ++d) acc[r][d] = fmaf(p4[r], g4[d], acc[r][d]);
        }
    }
#pragma unroll
    for (int r = 0; r < 4; ++r) {
        float4 v = {acc[r][0], acc[r][1], acc[r][2], acc[r][3]};
        *(float4*)&Wf[(size_t)(i0 + ti * 4 + r) * 328 + c0 + tj * 4] = v;
    }
}

// ---------------- pack Wf -> 3-way bf16 split, layout [A | B2 | 0 | B1], K=352 ----------------
__global__ void k_packWf3(const float* __restrict__ Wf, unsigned short* __restrict__ Bh,
                          unsigned short* __restrict__ Bm, unsigned short* __restrict__ Bl) {
    int idx = blockIdx.x * 256 + threadIdx.x; // 256*352 = 90112
    if (idx >= 90112) return;
    int n = idx / 352, k = idx - n * 352;
    float f;
    if (k < 256)      f = Wf[(size_t)n * 328 + k];               // A
    else if (k < 264) f = Wf[(size_t)n * 328 + 320 + (k - 256)]; // B2
    else if (k < 288) f = 0.f;                                    // pad
    else              f = Wf[(size_t)n * 328 + 256 + (k - 288)]; // B1
    unsigned short h = f2bf(f);
    float r1 = f - bf2f(h);
    unsigned short m = f2bf(r1);
    float r2 = r1 - bf2f(m);
    unsigned short l = f2bf(r2);
    Bh[idx] = h; Bm[idx] = m; Bl[idx] = l;
}

// ---------------- main 1a: base = [x|u|0] @ Bb^T + bv via bf16x3 MFMA ----------------
#define BSTR 296
__global__ void __launch_bounds__(256) k_base(const float* __restrict__ x, const float* __restrict__ u,
                                              const unsigned short* __restrict__ Bbh,
                                              const unsigned short* __restrict__ Bbm,
                                              const unsigned short* __restrict__ Bbl,
                                              const float* __restrict__ bv,
                                              float* __restrict__ wg) {
    __shared__ __align__(16) unsigned short Ah[32 * BSTR];
    __shared__ __align__(16) unsigned short Am[32 * BSTR];
    __shared__ __align__(16) unsigned short Al[32 * BSTR];
    const int tid = threadIdx.x;
    const int r0 = blockIdx.x * 32;
    {
        const float4* xg4 = (const float4*)(x + (size_t)r0 * 256);
#pragma unroll
        for (int i = 0; i < 8; ++i) {
            int e = tid + i * 256, r = e >> 6, c4 = e & 63;
            float4 v = xg4[e];
            float vv[4] = {v.x, v.y, v.z, v.w};
            u16x4 hv, mv, lv;
#pragma unroll
            for (int j = 0; j < 4; ++j) {
                unsigned short h = f2bf(vv[j]);
                float rr1 = vv[j] - bf2f(h);
                unsigned short m = f2bf(rr1);
                lv[j] = f2bf(rr1 - bf2f(m));
                hv[j] = h; mv[j] = m;
            }
            *(u16x4*)&Ah[r * BSTR + c4 * 4] = hv;
            *(u16x4*)&Am[r * BSTR + c4 * 4] = mv;
            *(u16x4*)&Al[r * BSTR + c4 * 4] = lv;
        }
    }
    if (tid < 64) {
        int r = tid >> 1, h4 = tid & 1;
        float4 v = *(const float4*)&u[(size_t)(r0 + r) * 8 + h4 * 4];
        float vv[4] = {v.x, v.y, v.z, v.w};
        u16x4 hv, mv, lv;
#pragma unroll
        for (int j = 0; j < 4; ++j) {
            unsigned short h = f2bf(vv[j]);
            float rr1 = vv[j] - bf2f(h);
            unsigned short m = f2bf(rr1);
            lv[j] = f2bf(rr1 - bf2f(m));
            hv[j] = h; mv[j] = m;
        }
        *(u16x4*)&Ah[r * BSTR + 256 + h4 * 4] = hv;
        *(u16x4*)&Am[r * BSTR + 256 + h4 * 4] = mv;
        *(u16x4*)&Al[r * BSTR + 256 + h4 * 4] = lv;
    }
    if (tid < 96) {
        int r = tid / 3, cc = tid - r * 3;
        u16x8 z = {0, 0, 0, 0, 0, 0, 0, 0};
        *(u16x8*)&Ah[r * BSTR + 264 + cc * 8] = z;
        *(u16x8*)&Am[r * BSTR + 264 + cc * 8] = z;
        *(u16x8*)&Al[r * BSTR + 264 + cc * 8] = z;
    }
    __syncthreads();

    const int lane = tid & 63, wid = tid >> 6;
    const int n0 = wid * 16;
    const int lr = lane & 15, lg = lane >> 4;
    const int lk = lg * 8;
    f32x4 acc[2];
    acc[0] = (f32x4){0.f, 0.f, 0.f, 0.f};
    acc[1] = (f32x4){0.f, 0.f, 0.f, 0.f};

    for (int kt = 0; kt < 9; ++kt) {
        const int ka = kt * 32 + lk;
        short8 a_h[2], a_m[2], a_l[2];
        a_h[0] = *(const short8*)&Ah[lr * BSTR + ka];
        a_h[1] = *(const short8*)&Ah[(16 + lr) * BSTR + ka];
        a_m[0] = *(const short8*)&Am[lr * BSTR + ka];
        a_m[1] = *(const short8*)&Am[(16 + lr) * BSTR + ka];
        a_l[0] = *(const short8*)&Al[lr * BSTR + ka];
        a_l[1] = *(const short8*)&Al[(16 + lr) * BSTR + ka];
        const size_t n = (size_t)(n0 + lr);
        short8 b_h = *(const short8*)&Bbh[n * 288 + ka];
        short8 b_m = *(const short8*)&Bbm[n * 288 + ka];
        short8 b_l = *(const short8*)&Bbl[n * 288 + ka];
#pragma unroll
        for (int m = 0; m < 2; ++m) {
            acc[m] = __builtin_amdgcn_mfma_f32_16x16x32_bf16(a_h[m], b_h, acc[m], 0, 0, 0);
            acc[m] = __builtin_amdgcn_mfma_f32_16x16x32_bf16(a_m[m], b_h, acc[m], 0, 0, 0);
            acc[m] = __builtin_amdgcn_mfma_f32_16x16x32_bf16(a_h[m], b_m, acc[m], 0, 0, 0);
            acc[m] = __builtin_amdgcn_mfma_f32_16x16x32_bf16(a_l[m], b_h, acc[m], 0, 0, 0);
            acc[m] = __builtin_amdgcn_mfma_f32_16x16x32_bf16(a_m[m], b_m, acc[m], 0, 0, 0);
            acc[m] = __builtin_amdgcn_mfma_f32_16x16x32_bf16(a_h[m], b_l, acc[m], 0, 0, 0);
        }
    }
    const float bvv = bv[n0 + lr];
#pragma unroll
    for (int m = 0; m < 2; ++m)
#pragma unroll
        for (int j = 0; j < 4; ++j)
            wg[(size_t)(r0 + m * 16 + lg * 4 + j) * 64 + n0 + lr] = acc[m][j] + bvv;
}

// ---------------- main 1b: per-row recurrence (in place on wg) ----------------
__global__ void __launch_bounds__(256) k_rec(float* __restrict__ wg, const float* __restrict__ D11g) {
    __shared__ float D[64 * 64];
    const int tid = threadIdx.x;
#pragma unroll
    for (int t = 0; t < 16; ++t) D[tid + t * 256] = D11g[tid + t * 256];
    __syncthreads();
    const size_t r = (size_t)blockIdx.x * 256 + tid;
    float w[64];
    float* wr = wg + r * 64;
#pragma unroll
    for (int c = 0; c < 16; ++c) {
        float4 v = *(const float4*)&wr[c * 4];
        w[4 * c] = v.x; w[4 * c + 1] = v.y; w[4 * c + 2] = v.z; w[4 * c + 3] = v.w;
    }
    w[0] = fmaxf(w[0], 0.f);
#pragma unroll
    for (int i = 1; i < 64; ++i) {
        float s0 = w[i], s1 = 0.f, s2 = 0.f, s3 = 0.f;
#pragma unroll
        for (int j = 0; j + 3 < i; j += 4) {
            s0 = fmaf(w[j + 0], D[i * 64 + j + 0], s0);
            s1 = fmaf(w[j + 1], D[i * 64 + j + 1], s1);
            s2 = fmaf(w[j + 2], D[i * 64 + j + 2], s2);
            s3 = fmaf(w[j + 3], D[i * 64 + j + 3], s3);
        }
#pragma unroll
        for (int j = i & ~3; j < i; ++j) s0 = fmaf(w[j], D[i * 64 + j], s0);
        w[i] = fmaxf((s0 + s1) + (s2 + s3), 0.f);
    }
#pragma unroll
    for (int c = 0; c < 16; ++c) {
        float4 v = {w[4 * c], w[4 * c + 1], w[4 * c + 2], w[4 * c + 3]};
        *(float4*)&wr[c * 4] = v;
    }
}

// ---------------- main 2: out = [x|u|0|w] @ WfP^T via tiered bf16x3-split MFMA ----------------
#define ASTR 360
__global__ void __launch_bounds__(256) k_m2(const float* __restrict__ x, const float* __restrict__ wg,
                                            const float* __restrict__ u,
                                            const unsigned short* __restrict__ Bh,
                                            const unsigned short* __restrict__ Bm,
                                            const unsigned short* __restrict__ Bl,
                                            float* __restrict__ out) {
    __shared__ __align__(16) unsigned short Ah[32 * ASTR];
    __shared__ __align__(16) unsigned short Am[32 * ASTR];
    __shared__ __align__(16) unsigned short Al[32 * ASTR];
    const int tid = threadIdx.x;
    const int r0 = blockIdx.x * 32;
    {
        const float4* xg4 = (const float4*)(x + (size_t)r0 * 256);
#pragma unroll
        for (int i = 0; i < 8; ++i) {
            int e = tid + i * 256, r = e >> 6, c4 = e & 63;
            float4 v = xg4[e];
            float vv[4] = {v.x, v.y, v.z, v.w};
            u16x4 hv, mv, lv;
#pragma unroll
            for (int j = 0; j < 4; ++j) {
                unsigned short h = f2bf(vv[j]);
                float rr1 = vv[j] - bf2f(h);
                unsigned short m = f2bf(rr1);
                lv[j] = f2bf(rr1 - bf2f(m));
                hv[j] = h; mv[j] = m;
            }
            *(u16x4*)&Ah[r * ASTR + c4 * 4] = hv;
            *(u16x4*)&Am[r * ASTR + c4 * 4] = mv;
            *(u16x4*)&Al[r * ASTR + c4 * 4] = lv;
        }
    }
    if (tid < 64) {
        int r = tid >> 1, h4 = tid & 1;
        float4 v = *(const float4*)&u[(size_t)(r0 + r) * 8 + h4 * 4];
        float vv[4] = {v.x, v.y, v.z, v.w};
        u16x4 hv, mv, lv;
#pragma unroll
        for (int j = 0; j < 4; ++j) {
            unsigned short h = f2bf(vv[j]);
            float rr1 = vv[j] - bf2f(h);
            unsigned short m = f2bf(rr1);
            lv[j] = f2bf(rr1 - bf2f(m));
            hv[j] = h; mv[j] = m;
        }
        *(u16x4*)&Ah[r * ASTR + 256 + h4 * 4] = hv;
        *(u16x4*)&Am[r * ASTR + 256 + h4 * 4] = mv;
        *(u16x4*)&Al[r * ASTR + 256 + h4 * 4] = lv;
    }
    if (tid < 96) {
        int r = tid / 3, cc = tid - r * 3;
        u16x8 z = {0, 0, 0, 0, 0, 0, 0, 0};
        *(u16x8*)&Ah[r * ASTR + 264 + cc * 8] = z;
        *(u16x8*)&Am[r * ASTR + 264 + cc * 8] = z;
        *(u16x8*)&Al[r * ASTR + 264 + cc * 8] = z;
    }
    {
        int r = tid >> 3, c8 = tid & 7;
        const float4* wp = (const float4*)&wg[(size_t)(r0 + r) * 64 + c8 * 8];
        float4 v0 = wp[0], v1 = wp[1];
        float vv[8] = {v0.x, v0.y, v0.z, v0.w, v1.x, v1.y, v1.z, v1.w};
        u16x8 hv, mv, lv;
#pragma unroll
        for (int j = 0; j < 8; ++j) {
            unsigned short h = f2bf(vv[j]);
            float rr1 = vv[j] - bf2f(h);
            unsigned short m = f2bf(rr1);
            lv[j] = f2bf(rr1 - bf2f(m));
            hv[j] = h; mv[j] = m;
        }
        *(u16x8*)&Ah[r * ASTR + 288 + c8 * 8] = hv;
        *(u16x8*)&Am[r * ASTR + 288 + c8 * 8] = mv;
        *(u16x8*)&Al[r * ASTR + 288 + c8 * 8] = lv;
    }
    __syncthreads();

    const int lane = tid & 63, wid = tid >> 6;
    const int n0 = wid * 64;
    const int lr = lane & 15, lg = lane >> 4;
    const int lk = lg * 8;
    f32x4 acc[2][4];
#pragma unroll
    for (int m = 0; m < 2; ++m)
#pragma unroll
        for (int nf = 0; nf < 4; ++nf) acc[m][nf] = (f32x4){0.f, 0.f, 0.f, 0.f};

    for (int kt = 0; kt < 11; ++kt) {
        const int ka = kt * 32 + lk;
        short8 a_h[2], a_m[2], a_l[2];
        a_h[0] = *(const short8*)&Ah[lr * ASTR + ka];
        a_h[1] = *(const short8*)&Ah[(16 + lr) * ASTR + ka];
        a_m[0] = *(const short8*)&Am[lr * ASTR + ka];
        a_m[1] = *(const short8*)&Am[(16 + lr) * ASTR + ka];
        a_l[0] = *(const short8*)&Al[lr * ASTR + ka];
        a_l[1] = *(const short8*)&Al[(16 + lr) * ASTR + ka];
        short8 b_h[4], b_m[4], b_l[4];
#pragma unroll
        for (int nf = 0; nf < 4; ++nf) {
            const size_t n = (size_t)(n0 + nf * 16 + lr);
            b_h[nf] = *(const short8*)&Bh[n * 352 + ka];
            b_m[nf] = *(const short8*)&Bm[n * 352 + ka];
            b_l[nf] = *(const short8*)&Bl[n * 352 + ka];
        }
        const bool wtile = (kt >= 9);
#pragma unroll
        for (int m = 0; m < 2; ++m)
#pragma unroll
            for (int nf = 0; nf < 4; ++nf) {
                acc[m][nf] = __builtin_amdgcn_mfma_f32_16x16x32_bf16(a_h[m], b_h[nf], acc[m][nf], 0, 0, 0);
                acc[m][nf] = __builtin_amdgcn_mfma_f32_16x16x32_bf16(a_m[m], b_h[nf], acc[m][nf], 0, 0, 0);
                acc[m][nf] = __builtin_amdgcn_mfma_f32_16x16x32_bf16(a_h[m], b_m[nf], acc[m][nf], 0, 0, 0);
                acc[m][nf] = __builtin_amdgcn_mfma_f32_16x16x32_bf16(a_l[m], b_h[nf], acc[m][nf], 0, 0, 0);
                acc[m][nf] = __builtin_amdgcn_mfma_f32_16x16x32_bf16(a_m[m], b_m[nf], acc[m][nf], 0, 0, 0);
                acc[m][nf] = __builtin_amdgcn_mfma_f32_16x16x32_bf16(a_h[m], b_l[nf], acc[m][nf], 0, 0, 0);
                if (wtile) {
                    acc[m][nf] = __builtin_amdgcn_mfma_f32_16x16x32_bf16(a_m[m], b_l[nf], acc[m][nf], 0, 0, 0);
                    acc[m][nf] = __builtin_amdgcn_mfma_f32_16x16x32_bf16(a_l[m], b_m[nf], acc[m][nf], 0, 0, 0);
                }
            }
    }
#pragma unroll
    for (int m = 0; m < 2; ++m)
#pragma unroll
        for (int nf = 0; nf < 4; ++nf)
#pragma unroll
            for (int j = 0; j < 4; ++j)
                out[(size_t)(r0 + m * 16 + lg * 4 + j) * 256 + n0 + nf * 16 + lr] = acc[m][nf][j];
}

extern "C" void kernel_launch(void* const* d_in, const int* in_sizes, int n_in,
                              void* d_out, int out_size, void* d_ws, size_t ws_size,
                              hipStream_t stream) {
    const float* x   = (const float*)d_in[0];
    const float* u   = (const float*)d_in[1];
    const float* Xm  = (const float*)d_in[2];
    const float* Um  = (const float*)d_in[3];
    const float* Y1  = (const float*)d_in[4];
    const float* XPm = (const float*)d_in[5];
    const float* B2  = (const float*)d_in[6];
    const float* D12 = (const float*)d_in[7];
    const float* bv  = (const float*)d_in[8];
    float* out = (float*)d_out;
    float* ws  = (float*)d_ws;

    float* H    = ws + WS_H;
    float* C    = ws + WS_C;
    float* T    = ws + WS_T;
    float* R    = ws + WS_R;
    float* W    = ws + WS_W;
    float* E    = ws + WS_E;
    float* Y    = ws + WS_Y;
    float* RHS  = ws + WS_RHS;
    float* C1T  = ws + WS_C1T;
    float* D11g = ws + WS_D11;
    float* Wf   = ws + WS_WF;
    unsigned short* Bh  = (unsigned short*)(ws + WS_WFH);
    unsigned short* Bm  = (unsigned short*)(ws + WS_WFM);
    unsigned short* Bl  = (unsigned short*)(ws + WS_WFL);
    unsigned short* Bbh = (unsigned short*)(ws + WS_BBH);
    unsigned short* Bbm = (unsigned short*)(ws + WS_BBM);
    unsigned short* Bbl = (unsigned short*)(ws + WS_BBL);
    float* wg = ws + WS_WG;

    k_build<<<656, 256, 0, stream>>>(Xm, XPm, H, C);
    k_derived<<<408, 256, 0, stream>>>(H, Um, Y1, B2, Y, RHS, C1T, D11g, Wf);
    k_packBb<<<72, 256, 0, stream>>>(C1T, D12, Bbh, Bbm, Bbl);
    k_base<<<2048, 256, 0, stream>>>(x, u, Bbh, Bbm, Bbl, bv, wg);
    k_rec<<<256, 256, 0, stream>>>(wg, D11g);
    for (int b = 0; b < 4; ++b) {
        k_inv64<<<1, 256, 0, stream>>>(C, E, b);
        k_gjT<<<8, 256, 0, stream>>>(C, E, T, R, W, b);
        k_gjU<<<16, 256, 0, stream>>>(C, T, R, W, b);
    }
    k_apply<<<20, 256, 0, stream>>>(C, Y, RHS, Wf);
    k_packWf3<<<352, 256, 0, stream>>>(Wf, Bh, Bm, Bl);
    k_m2<<<2048, 256, 0, stream>>>(x, wg, u, Bh, Bm, Bl, out);
}